// Round 4
// baseline (145.364 us; speedup 1.0000x reference)
//
#include <hip/hip_runtime.h>
#include <stdint.h>

// KAN layer as bf16 MFMA GEMM: out = phi @ W^T + bias
//   phi[b, i*8+g] = normalized cubic-bump basis (g<5; 3 zero-pad cols)
// M=32768, N=256, K=2048 (16 chunks x BK=128, 4 ktr-phases of K=32 each).
// R11: mrep=2 B-register-reuse. R10 showed N-splitting duplicates basis
//   VALU (dupN 2->4 regressed). Floors per CU: MFMA 13.7us, LDS-B-reads
//   20.5/mrep us, VALU 3.7*dupN us. Only (mrep=2, nrep=4) beats R7's
//   20.5us LDS floor while keeping dupN=2: wave = 64 rows x 128 cols,
//   acc[2][4] = 128 VGPR, grid (128,2) = 256 blocks = 1 wave/SIMD.
//   At 1 wave/SIMD the VGPR file is all ours (512) -> no spill pressure,
//   and per-K32 the wave issues 16 MFMA (512 pipe-cyc) vs ~300 cyc VALU
//   -> MFMA-bound with pure ILP. Sync = R10's verified counted-vmcnt
//   pattern (vmcnt(16): 8 x-loads + 8 DMAs per chunk in flight across
//   the barrier). Also: prep minmax 2048 blocks x 4 indep float4s.

#define B_SZ   32768
#define IN_SZ  256
#define OUT_SZ 256
#define EPSF   1e-8f
#define NMB    2048   // minmax partial blocks

typedef __bf16 bf16x8 __attribute__((ext_vector_type(8)));
typedef unsigned short ushort8 __attribute__((ext_vector_type(8)));
typedef float floatx16 __attribute__((ext_vector_type(16)));

union frag_u { uint4 u; bf16x8 v; };

__device__ __forceinline__ unsigned short f2bf(float f) {
  unsigned u = __float_as_uint(f);
  u += 0x7FFFu + ((u >> 16) & 1u);
  return (unsigned short)(u >> 16);
}

// Wf fragment-order chunk index for (o, i): 16B chunk = 8 bf16 g-slots.
//   chunk = ((oT*64 + kt)*2 + ks)*64 + lane, o=oT*32+(lane&31), i=kt*4+ks*2+(lane>>5)

// Fused prep: blocks [0,256) pack W into fragment order; [256,256+NMB) do
// per-block min/max partials of x (4 independent float4s per thread).
__global__ void __launch_bounds__(256) prep_kernel(const float* __restrict__ coef,
                                                   const float* __restrict__ scale,
                                                   const float* __restrict__ x,
                                                   unsigned short* __restrict__ wf,
                                                   float* __restrict__ part, int n4) {
  const int t = threadIdx.x;
  if (blockIdx.x < 256) {
    int idx = blockIdx.x * 256 + t;        // o*256 + i
    int o = idx >> 8, i = idx & 255;
    float s = scale[idx];
    const float* c = coef + (size_t)idx * 5;
    ushort8 v;
    v[0] = f2bf(c[0] * s); v[1] = f2bf(c[1] * s); v[2] = f2bf(c[2] * s);
    v[3] = f2bf(c[3] * s); v[4] = f2bf(c[4] * s);
    v[5] = 0; v[6] = 0; v[7] = 0;
    int chunk = (((o >> 5) * 64 + (i >> 2)) * 2 + ((i >> 1) & 1)) * 64
                + (i & 1) * 32 + (o & 31);
    *(ushort8*)(wf + (size_t)chunk * 8) = v;
  } else {
    int mb = blockIdx.x - 256;             // [0, NMB)
    const float4* x4 = (const float4*)x;
    // n4 = 2097152 = 4 * NMB * 256 exactly: 4 independent strided loads.
    int i = mb * 256 + t;
    float lmin = 1e30f, lmax = -1e30f;
    #pragma unroll
    for (int k = 0; k < 4; ++k) {
      float4 v = x4[i + k * (NMB * 256)];
      lmin = fminf(lmin, fminf(fminf(v.x, v.y), fminf(v.z, v.w)));
      lmax = fmaxf(lmax, fmaxf(fmaxf(v.x, v.y), fmaxf(v.z, v.w)));
    }
    #pragma unroll
    for (int off = 32; off >= 1; off >>= 1) {
      lmin = fminf(lmin, __shfl_down(lmin, off, 64));
      lmax = fmaxf(lmax, __shfl_down(lmax, off, 64));
    }
    __shared__ float smn[4], smx[4];
    if ((t & 63) == 0) { smn[t >> 6] = lmin; smx[t >> 6] = lmax; }
    __syncthreads();
    if (t == 0) {
      part[2 * mb]     = fminf(fminf(smn[0], smn[1]), fminf(smn[2], smn[3]));
      part[2 * mb + 1] = fmaxf(fmaxf(smx[0], smx[1]), fmaxf(smx[2], smx[3]));
    }
  }
}

// Lean basis octet: ~33 VALU. where(d<1,1-d^3,0) == max(1-d*d*|d|,0) (d>=0
// monotone). eps dropped: sum >= 0.98 always (nearest knot <= 0.25 away).
// bf16 pack by truncation: v_perm_b32 grabs high16 pairs (err <= 2^-8 rel,
// inside the 7.1e-2 budget; measured absmax headroom 4.5x).
__device__ __forceinline__ bf16x8 basisfrag(float xval, float scA, float scB) {
  float xn = fmaf(xval, scA, scB);
  float d0 = xn + 1.0f, d1 = xn + 0.5f, d3 = xn - 0.5f, d4 = xn - 1.0f;
  float b0 = fmaxf(fmaf(d0 * d0, -fabsf(d0), 1.0f), 0.0f);
  float b1 = fmaxf(fmaf(d1 * d1, -fabsf(d1), 1.0f), 0.0f);
  float b2 = fmaxf(fmaf(xn * xn, -fabsf(xn), 1.0f), 0.0f);
  float b3 = fmaxf(fmaf(d3 * d3, -fabsf(d3), 1.0f), 0.0f);
  float b4 = fmaxf(fmaf(d4 * d4, -fabsf(d4), 1.0f), 0.0f);
  float sum = ((b0 + b1) + (b2 + b3)) + b4;
  float inv = __builtin_amdgcn_rcpf(sum);
  b0 *= inv; b1 *= inv; b2 *= inv; b3 *= inv; b4 *= inv;
  frag_u r;
  r.u.x = __builtin_amdgcn_perm(__float_as_uint(b1), __float_as_uint(b0), 0x07060302u);
  r.u.y = __builtin_amdgcn_perm(__float_as_uint(b3), __float_as_uint(b2), 0x07060302u);
  r.u.z = __float_as_uint(b4) >> 16;
  r.u.w = 0u;
  return r.v;
}

__global__ void __launch_bounds__(256, 1) kan_gemm(
    const float* __restrict__ x,            // [32768][256]
    const unsigned short* __restrict__ wf,  // fragment-ordered W, 1 MB
    const float* __restrict__ bias,         // [256]
    const float* __restrict__ part,         // NMB {min,max} partials
    float* __restrict__ out)                // [32768][256]
{
  // B chunk buffers: [buf][ (ni*4+ktr)*2+ks ][ lane*16B ]  -> 2 x 32 KB
  __shared__ __align__(16) unsigned short Bb[2][16384];
  __shared__ float2 red[4];

  const int t = threadIdx.x;
  const int lane = t & 63;
  const int wm = t >> 6;                     // 4 waves stacked in m
  const int l31 = lane & 31, lh = lane >> 5;
  const int bRow = blockIdx.x * 256;         // 256-row M tile
  const int bCol = blockIdx.y * 128;
  const int row0 = bRow + wm * 64 + l31;     // strip 0 row; strip 1 = +32

  // ---- B chunk staging: 32 segments of 1 KB; each wave DMAs 8 (lane-linear) ----
  auto stage = [&](int c, int buf) {
    #pragma unroll
    for (int r = 0; r < 8; ++r) {
      int idx = r * 4 + wm;                  // wave-uniform
      const unsigned short* src = wf +
          ((size_t)(((blockIdx.y * 4 + (idx >> 3)) * 64 + (c * 4 + ((idx >> 1) & 3))) * 2
                    + (idx & 1))) * 512 + (size_t)lane * 8;
      __builtin_amdgcn_global_load_lds(
          (const __attribute__((address_space(1))) unsigned int*)src,
          (__attribute__((address_space(3))) unsigned int*)(&Bb[buf][idx * 512 + lane * 8]),
          16, 0, 0);
    }
  };

  const float* xrow0 = x + (size_t)row0 * IN_SZ;
  const float* xrow1 = xrow0 + 32 * IN_SZ;

  // prologue: chunk 0 DMA + chunk-0 x loads in flight during minmax reduce
  // (the reduce's __syncthreads drains them once -- one-time cost).
  stage(0, 0);
  float4 xq0[4], xq1[4], xqn0[4], xqn1[4];
  #pragma unroll
  for (int g = 0; g < 4; ++g) {
    xq0[g] = *(const float4*)(xrow0 + g * 4);
    xq1[g] = *(const float4*)(xrow1 + g * 4);
  }

  float mn = 1e30f, mx = -1e30f;
  const float2* part2 = (const float2*)part;
  #pragma unroll
  for (int k = 0; k < NMB / 256; ++k) {
    float2 p = part2[k * 256 + t];
    mn = fminf(mn, p.x); mx = fmaxf(mx, p.y);
  }
  #pragma unroll
  for (int off = 32; off >= 1; off >>= 1) {
    mn = fminf(mn, __shfl_down(mn, off, 64));
    mx = fmaxf(mx, __shfl_down(mx, off, 64));
  }
  if (lane == 0) red[wm] = make_float2(mn, mx);
  __syncthreads();
  mn = fminf(fminf(red[0].x, red[1].x), fminf(red[2].x, red[3].x));
  mx = fmaxf(fmaxf(red[0].y, red[1].y), fmaxf(red[2].y, red[3].y));
  const float scA = 2.0f / (mx - mn + EPSF);
  const float scB = -mn * scA - 1.0f;

  floatx16 acc0[4] = {}, acc1[4] = {};       // [strip][ni]
  bf16x8 br[2][8];                           // [ktr parity][ni*2+ks]

  auto ldsB = [&](int ktr, int buf, bf16x8* dst) {
    #pragma unroll
    for (int q = 0; q < 8; ++q) {            // q = ni*2+ks
      int ni = q >> 1, ks = q & 1;
      dst[q] = *(const bf16x8*)(&Bb[buf][((ni * 4 + ktr) * 2 + ks) * 512 + lane * 8]);
    }
  };

  // ---- K loop: 16 chunks x 4 ktr-phases; counted vmcnt, no drain ----
  for (int c = 0; c < 16; ++c) {
    const int buf = c & 1;

    if (c < 15) {
      // issue next chunk's loads; they stay in flight across the barrier
      #pragma unroll
      for (int g = 0; g < 4; ++g) {
        xqn0[g] = *(const float4*)(xrow0 + (c + 1) * 16 + g * 4);
        xqn1[g] = *(const float4*)(xrow1 + (c + 1) * 16 + g * 4);
      }
      stage(c + 1, buf ^ 1);
    }
    __builtin_amdgcn_sched_barrier(0);       // pin issues above the wait
    // newest 16 in flight = {8 xqn + 8 DMA} for chunk c+1; everything older
    // (chunk c's 16, issued a full chunk ago) must retire -> LDS data ready.
    if (c < 15) asm volatile("s_waitcnt vmcnt(16)");
    else        asm volatile("s_waitcnt vmcnt(0)");
    __builtin_amdgcn_s_barrier();
    __builtin_amdgcn_sched_barrier(0);       // no ds_read hoists above barrier

    ldsB(0, buf, br[0]);                     // chunk-leading fragment load

    #pragma unroll
    for (int ktr = 0; ktr < 4; ++ktr) {
      if (ktr < 3) ldsB(ktr + 1, buf, br[(ktr + 1) & 1]);  // prefetch next ktr

      // A fragments from registers: i = (c*4+ktr)*4 + ks*2 + lh
      float xv00 = lh ? xq0[ktr].y : xq0[ktr].x;   // strip0 ks=0
      float xv01 = lh ? xq0[ktr].w : xq0[ktr].z;   // strip0 ks=1
      float xv10 = lh ? xq1[ktr].y : xq1[ktr].x;   // strip1 ks=0
      float xv11 = lh ? xq1[ktr].w : xq1[ktr].z;   // strip1 ks=1
      bf16x8 a00 = basisfrag(xv00, scA, scB);
      bf16x8 a01 = basisfrag(xv01, scA, scB);
      bf16x8 a10 = basisfrag(xv10, scA, scB);
      bf16x8 a11 = basisfrag(xv11, scA, scB);

      bf16x8* Bf = br[ktr & 1];
      __builtin_amdgcn_s_setprio(1);
      // ks=0 wave of 8 independent MFMAs, then ks=1 (depth-2 acc chains)
      #pragma unroll
      for (int ni = 0; ni < 4; ++ni) {
        acc0[ni] = __builtin_amdgcn_mfma_f32_32x32x16_bf16(a00, Bf[ni * 2 + 0], acc0[ni], 0, 0, 0);
        acc1[ni] = __builtin_amdgcn_mfma_f32_32x32x16_bf16(a10, Bf[ni * 2 + 0], acc1[ni], 0, 0, 0);
      }
      #pragma unroll
      for (int ni = 0; ni < 4; ++ni) {
        acc0[ni] = __builtin_amdgcn_mfma_f32_32x32x16_bf16(a01, Bf[ni * 2 + 1], acc0[ni], 0, 0, 0);
        acc1[ni] = __builtin_amdgcn_mfma_f32_32x32x16_bf16(a11, Bf[ni * 2 + 1], acc1[ni], 0, 0, 0);
      }
      __builtin_amdgcn_s_setprio(0);
    }

    if (c < 15) {
      #pragma unroll
      for (int g = 0; g < 4; ++g) { xq0[g] = xqn0[g]; xq1[g] = xqn1[g]; }
      // read-done fence: all waves' ds_reads of buf precede their MFMAs
      // (in-order issue + compiler lgkm waits), so a bare barrier suffices
      // before top-of-(c+1) stage(c+2) overwrites buf.
      __builtin_amdgcn_sched_barrier(0);
      __builtin_amdgcn_s_barrier();
      __builtin_amdgcn_sched_barrier(0);
    }
  }

  // epilogue: C/D col=lane&31, row=(reg&3)+8*(reg>>2)+4*(lane>>5) [m74/m101]
  #pragma unroll
  for (int ni = 0; ni < 4; ++ni) {
    int o = bCol + ni * 32 + l31;
    float bs = bias[o];
    int rb = bRow + wm * 64 + 4 * lh;
    #pragma unroll
    for (int reg = 0; reg < 16; ++reg) {
      int r = rb + (reg & 3) + 8 * (reg >> 2);
      out[(size_t)r * OUT_SZ + o] = acc0[ni][reg] + bs;
      out[(size_t)(r + 32) * OUT_SZ + o] = acc1[ni][reg] + bs;
    }
  }
}

extern "C" void kernel_launch(void* const* d_in, const int* in_sizes, int n_in,
                              void* d_out, int out_size, void* d_ws, size_t ws_size,
                              hipStream_t stream) {
  const float* x     = (const float*)d_in[0];
  // d_in[1] = grid: linspace(-1,1,5), hardcoded
  const float* coef  = (const float*)d_in[2];
  const float* scale = (const float*)d_in[3];
  const float* bias  = (const float*)d_in[4];
  float* out = (float*)d_out;

  // ws: [0..NMB*8) minmax partials (NMB float2), [16384..) Wf (1 MB)
  size_t need = 16384 + (size_t)OUT_SZ * IN_SZ * 8 * 2;
  if (ws_size < need) return;

  float* part = (float*)d_ws;
  unsigned short* wf = (unsigned short*)((char*)d_ws + 16384);

  prep_kernel<<<256 + NMB, 256, 0, stream>>>(coef, scale, x, wf, part,
                                             (B_SZ * IN_SZ) / 4);
  dim3 g(B_SZ / 256, OUT_SZ / 128);
  kan_gemm<<<g, 256, 0, stream>>>(x, wf, bias, part, out);
}

// Round 5
// 143.409 us; speedup vs baseline: 1.0136x; 1.0136x over previous
//
#include <hip/hip_runtime.h>
#include <stdint.h>

// KAN layer as bf16 MFMA GEMM: out = phi @ W^T + bias
//   phi[b, i*8+g] = normalized cubic-bump basis (g<5; 3 zero-pad cols)
// M=32768, N=256, K=2048 (32 chunks x BK=64, 2 ktr-phases of K=32 each).
// R12: 16x16x32 MFMA to break the occupancy<->dupN lock. With 32-row
//   strips (32x32 MFMA), waves/SIMD = 256/N_wave = dupN (R7: 2/2; R10:
//   ~2.4/4 regressed; R11: 1/1 regressed hard -> latency-bound regime).
//   16-row strips give 4 waves/SIMD at dupN=2: wave = 16 rows x 128 cols,
//   block = 4 waves = 64x128, grid (512,2) = 1024 blocks = 4 blocks/CU
//   (LDS 2x16KB = 33KB caps exactly at 4). Basis VALU, LDS traffic, and
//   x traffic are invariant vs R7; MFMA floor 13.8 -> 16.6us (16x16
//   ubench 2075 TF) but latency hiding doubles. VGPR must stay <=128.
//   Sync = R10/R11-verified counted-vmcnt (vmcnt(6): 2 x-scalars + 4
//   DMAs in flight across the barrier; never drain in main loop).

#define B_SZ   32768
#define IN_SZ  256
#define OUT_SZ 256
#define EPSF   1e-8f
#define NMB    2048   // minmax partial blocks

typedef __bf16 bf16x8 __attribute__((ext_vector_type(8)));
typedef unsigned short ushort8 __attribute__((ext_vector_type(8)));
typedef float floatx4 __attribute__((ext_vector_type(4)));

union frag_u { uint4 u; bf16x8 v; };

__device__ __forceinline__ unsigned short f2bf(float f) {
  unsigned u = __float_as_uint(f);
  u += 0x7FFFu + ((u >> 16) & 1u);
  return (unsigned short)(u >> 16);
}

// wf layout: [cb 0..15][i 0..255][om 0..15] of 16B (8 bf16 g-slots), 1 MB.
//   W[o][i][g] at wf + ((cb*256 + i)*16 + om)*8 shorts, o = cb*16 + om.
// B-frag (16x16x32): lane l holds col = l&15 (om), k = (l>>4)*8 + j, i.e.
//   i = i0 + (l>>4), g = j -> segment = contiguous 1KB, lane-linear. DMA-able.

// Fused prep: blocks [0,256) pack W into fragment order; [256,256+NMB) do
// per-block min/max partials of x (4 independent float4s per thread).
__global__ void __launch_bounds__(256) prep_kernel(const float* __restrict__ coef,
                                                   const float* __restrict__ scale,
                                                   const float* __restrict__ x,
                                                   unsigned short* __restrict__ wf,
                                                   float* __restrict__ part, int n4) {
  const int t = threadIdx.x;
  if (blockIdx.x < 256) {
    int idx = blockIdx.x * 256 + t;        // o*256 + i
    int o = idx >> 8, i = idx & 255;
    float s = scale[idx];
    const float* c = coef + (size_t)idx * 5;
    ushort8 v;
    v[0] = f2bf(c[0] * s); v[1] = f2bf(c[1] * s); v[2] = f2bf(c[2] * s);
    v[3] = f2bf(c[3] * s); v[4] = f2bf(c[4] * s);
    v[5] = 0; v[6] = 0; v[7] = 0;
    int cb = o >> 4, om = o & 15;
    *(ushort8*)(wf + ((size_t)((cb * 256 + i) * 16 + om)) * 8) = v;
  } else {
    int mb = blockIdx.x - 256;             // [0, NMB)
    const float4* x4 = (const float4*)x;
    // n4 = 2097152 = 4 * NMB * 256 exactly: 4 independent strided loads.
    int i = mb * 256 + t;
    float lmin = 1e30f, lmax = -1e30f;
    #pragma unroll
    for (int k = 0; k < 4; ++k) {
      float4 v = x4[i + k * (NMB * 256)];
      lmin = fminf(lmin, fminf(fminf(v.x, v.y), fminf(v.z, v.w)));
      lmax = fmaxf(lmax, fmaxf(fmaxf(v.x, v.y), fmaxf(v.z, v.w)));
    }
    #pragma unroll
    for (int off = 32; off >= 1; off >>= 1) {
      lmin = fminf(lmin, __shfl_down(lmin, off, 64));
      lmax = fmaxf(lmax, __shfl_down(lmax, off, 64));
    }
    __shared__ float smn[4], smx[4];
    if ((t & 63) == 0) { smn[t >> 6] = lmin; smx[t >> 6] = lmax; }
    __syncthreads();
    if (t == 0) {
      part[2 * mb]     = fminf(fminf(smn[0], smn[1]), fminf(smn[2], smn[3]));
      part[2 * mb + 1] = fmaxf(fmaxf(smx[0], smx[1]), fmaxf(smx[2], smx[3]));
    }
  }
}

// Lean basis octet: ~33 VALU. where(d<1,1-d^3,0) == max(1-d*d*|d|,0) (d>=0
// monotone). eps dropped: sum >= 0.98 always (nearest knot <= 0.25 away).
// bf16 pack by truncation: v_perm_b32 grabs high16 pairs (err <= 2^-8 rel,
// inside the 7.1e-2 budget; measured absmax headroom 4.5x).
__device__ __forceinline__ bf16x8 basisfrag(float xval, float scA, float scB) {
  float xn = fmaf(xval, scA, scB);
  float d0 = xn + 1.0f, d1 = xn + 0.5f, d3 = xn - 0.5f, d4 = xn - 1.0f;
  float b0 = fmaxf(fmaf(d0 * d0, -fabsf(d0), 1.0f), 0.0f);
  float b1 = fmaxf(fmaf(d1 * d1, -fabsf(d1), 1.0f), 0.0f);
  float b2 = fmaxf(fmaf(xn * xn, -fabsf(xn), 1.0f), 0.0f);
  float b3 = fmaxf(fmaf(d3 * d3, -fabsf(d3), 1.0f), 0.0f);
  float b4 = fmaxf(fmaf(d4 * d4, -fabsf(d4), 1.0f), 0.0f);
  float sum = ((b0 + b1) + (b2 + b3)) + b4;
  float inv = __builtin_amdgcn_rcpf(sum);
  b0 *= inv; b1 *= inv; b2 *= inv; b3 *= inv; b4 *= inv;
  frag_u r;
  r.u.x = __builtin_amdgcn_perm(__float_as_uint(b1), __float_as_uint(b0), 0x07060302u);
  r.u.y = __builtin_amdgcn_perm(__float_as_uint(b3), __float_as_uint(b2), 0x07060302u);
  r.u.z = __float_as_uint(b4) >> 16;
  r.u.w = 0u;
  return r.v;
}

__global__ void __launch_bounds__(256, 4) kan_gemm(
    const float* __restrict__ x,            // [32768][256]
    const unsigned short* __restrict__ wf,  // fragment-ordered W, 1 MB
    const float* __restrict__ bias,         // [256]
    const float* __restrict__ part,         // NMB {min,max} partials
    float* __restrict__ out)                // [32768][256]
{
  // B chunk buffers: [buf][ s = ktr*8+q ][ lane*16B ] -> 2 x 16 KB
  __shared__ __align__(16) unsigned short Bb[2][8192];
  __shared__ float2 red[4];

  const int t = threadIdx.x;
  const int lane = t & 63;
  const int wm = t >> 6;                     // 4 waves stacked in m
  const int l15 = lane & 15, koff = lane >> 4;   // row-in-strip, k-quarter
  const int bRow = blockIdx.x * 64;
  const int bCol = blockIdx.y * 128;
  const int row = bRow + wm * 16 + l15;      // this lane's A row

  // ---- B chunk staging: 16 segments of 1 KB; each wave DMAs 4 (lane-linear) ----
  auto stage = [&](int c, int buf) {
    #pragma unroll
    for (int r = 0; r < 4; ++r) {
      int s = r * 4 + wm;                    // wave-uniform; s = ktr*8 + q
      int cb = blockIdx.y * 8 + (s & 7);
      int i0 = c * 8 + (s >> 3) * 4;
      const unsigned short* src = wf + ((size_t)(cb * 256 + i0) * 16) * 8
                                     + (size_t)lane * 8;
      __builtin_amdgcn_global_load_lds(
          (const __attribute__((address_space(1))) unsigned int*)src,
          (__attribute__((address_space(3))) unsigned int*)(&Bb[buf][s * 512 + lane * 8]),
          16, 0, 0);
    }
  };

  const float* xrow = x + (size_t)row * IN_SZ;

  // prologue: chunk 0 DMA + chunk-0 x scalars in flight during minmax reduce
  // (the reduce's __syncthreads drains them once -- one-time cost).
  float xc0 = xrow[koff];
  float xc1 = xrow[4 + koff];
  stage(0, 0);

  float mn = 1e30f, mx = -1e30f;
  const float2* part2 = (const float2*)part;
  #pragma unroll
  for (int k = 0; k < NMB / 256; ++k) {
    float2 p = part2[k * 256 + t];
    mn = fminf(mn, p.x); mx = fmaxf(mx, p.y);
  }
  #pragma unroll
  for (int off = 32; off >= 1; off >>= 1) {
    mn = fminf(mn, __shfl_down(mn, off, 64));
    mx = fmaxf(mx, __shfl_down(mx, off, 64));
  }
  if (lane == 0) red[wm] = make_float2(mn, mx);
  __syncthreads();
  mn = fminf(fminf(red[0].x, red[1].x), fminf(red[2].x, red[3].x));
  mx = fmaxf(fmaxf(red[0].y, red[1].y), fmaxf(red[2].y, red[3].y));
  const float scA = 2.0f / (mx - mn + EPSF);
  const float scB = -mn * scA - 1.0f;

  floatx4 acc[8] = {};                       // [q] -> cols q*16..q*16+15
  bf16x8 bf[8];

  auto ldsB = [&](int ktr, int buf) {
    #pragma unroll
    for (int q = 0; q < 8; ++q)
      bf[q] = *(const bf16x8*)(&Bb[buf][(ktr * 8 + q) * 512 + lane * 8]);
  };

  // ---- K loop: 32 chunks x 2 ktr-phases; counted vmcnt, no drain ----
  for (int c = 0; c < 32; ++c) {
    const int buf = c & 1;
    float xn0, xn1;

    if (c < 31) {
      // issue next chunk's loads (x scalars FIRST, so the bottom copy's
      // implicit wait is vmcnt(4), keeping the DMAs in flight)
      xn0 = xrow[(c + 1) * 8 + koff];
      xn1 = xrow[(c + 1) * 8 + 4 + koff];
      stage(c + 1, buf ^ 1);
    }
    __builtin_amdgcn_sched_barrier(0);       // pin issues above the wait
    // newest 6 in flight = {2 x + 4 DMA} for chunk c+1; everything older
    // (chunk c's 6, issued a full chunk ago) must retire -> LDS data ready.
    if (c < 31) asm volatile("s_waitcnt vmcnt(6)");
    else        asm volatile("s_waitcnt vmcnt(0)");
    __builtin_amdgcn_s_barrier();
    __builtin_amdgcn_sched_barrier(0);       // no ds_read hoists above barrier

    // ---- ktr = 0: i = c*8 + koff ----
    ldsB(0, buf);
    {
      bf16x8 a = basisfrag(xc0, scA, scB);
      __builtin_amdgcn_s_setprio(1);
      #pragma unroll
      for (int q = 0; q < 8; ++q)
        acc[q] = __builtin_amdgcn_mfma_f32_16x16x32_bf16(a, bf[q], acc[q], 0, 0, 0);
      __builtin_amdgcn_s_setprio(0);
    }
    // ---- ktr = 1: i = c*8 + 4 + koff ----
    ldsB(1, buf);
    {
      bf16x8 a = basisfrag(xc1, scA, scB);
      __builtin_amdgcn_s_setprio(1);
      #pragma unroll
      for (int q = 0; q < 8; ++q)
        acc[q] = __builtin_amdgcn_mfma_f32_16x16x32_bf16(a, bf[q], acc[q], 0, 0, 0);
      __builtin_amdgcn_s_setprio(0);
    }

    if (c < 31) {
      xc0 = xn0; xc1 = xn1;
      // read-done fence: all waves' ds_reads of buf complete before their
      // final MFMA (compiler lgkm waits), which precedes this barrier; so
      // next chunk's stage(c+2) may overwrite buf after it.
      __builtin_amdgcn_sched_barrier(0);
      __builtin_amdgcn_s_barrier();
      __builtin_amdgcn_sched_barrier(0);
    }
  }

  // epilogue: C/D (16x16): col = lane&15, row = (lane>>4)*4 + reg [m89/m91]
  #pragma unroll
  for (int q = 0; q < 8; ++q) {
    int o = bCol + q * 16 + l15;
    float bs = bias[o];
    int rb = bRow + wm * 16 + koff * 4;
    #pragma unroll
    for (int reg = 0; reg < 4; ++reg)
      out[(size_t)(rb + reg) * OUT_SZ + o] = acc[q][reg] + bs;
  }
}

extern "C" void kernel_launch(void* const* d_in, const int* in_sizes, int n_in,
                              void* d_out, int out_size, void* d_ws, size_t ws_size,
                              hipStream_t stream) {
  const float* x     = (const float*)d_in[0];
  // d_in[1] = grid: linspace(-1,1,5), hardcoded
  const float* coef  = (const float*)d_in[2];
  const float* scale = (const float*)d_in[3];
  const float* bias  = (const float*)d_in[4];
  float* out = (float*)d_out;

  // ws: [0..NMB*8) minmax partials (NMB float2), [16384..) Wf (1 MB)
  size_t need = 16384 + (size_t)OUT_SZ * IN_SZ * 8 * 2;
  if (ws_size < need) return;

  float* part = (float*)d_ws;
  unsigned short* wf = (unsigned short*)((char*)d_ws + 16384);

  prep_kernel<<<256 + NMB, 256, 0, stream>>>(coef, scale, x, wf, part,
                                             (B_SZ * IN_SZ) / 4);
  dim3 g(B_SZ / 64, OUT_SZ / 128);
  kan_gemm<<<g, 256, 0, stream>>>(x, wf, bias, part, out);
}

// Round 6
// 140.390 us; speedup vs baseline: 1.0354x; 1.0215x over previous
//
#include <hip/hip_runtime.h>
#include <stdint.h>

// KAN layer as bf16 MFMA GEMM: out = phi @ W^T + bias
//   phi[b, i*8+g] = normalized cubic-bump basis (g<5; 3 zero-pad cols)
// M=32768, N=256, K=2048.
// R13: split-K=2 inside the block. Verified identity: waves/SIMD =
//   splitK*dupN/mrep. R7 (splitK=1,dupN=2,mrep=1) is locked at 2/SIMD;
//   R10 (dupN=4) drowned in VALU; R11 (mrep=2) died at 1/SIMD; R12
//   (16x16 MFMA) doubled the LDS floor (1KB B-frag = 16 kFLOP vs 32).
//   This config: 32x32 MFMA, block = 4 waves = 2 M-strips x 2 K-halves,
//   64x128 output, 32 chunks of BK=32 per half; grid (512,2) = 1024
//   blocks = 4 blocks/CU = 4 waves/SIMD at dupN=2, mrep=1. LDS floor
//   ~27us/CU (reads 4MB @85B/cyc + DMA 2MB @128B/cyc); R12 showed this
//   structure runs ~62% of LDS floor at 4 waves/SIMD -> target ~36us.
//   K-halves combined in epilogue via balanced LDS exchange (each wave
//   exports 2 acc tiles, imports partner's 2, stores 64 cols).
//   Sync = R12-verified counted-vmcnt (vmcnt(5): 1 x-float4 + 4 DMAs
//   in flight across the barrier; never drain in main loop).

#define B_SZ   32768
#define IN_SZ  256
#define OUT_SZ 256
#define EPSF   1e-8f
#define NMB    2048   // minmax partial blocks

typedef __bf16 bf16x8 __attribute__((ext_vector_type(8)));
typedef unsigned short ushort8 __attribute__((ext_vector_type(8)));
typedef float floatx16 __attribute__((ext_vector_type(16)));

union frag_u { uint4 u; bf16x8 v; };

__device__ __forceinline__ unsigned short f2bf(float f) {
  unsigned u = __float_as_uint(f);
  u += 0x7FFFu + ((u >> 16) & 1u);
  return (unsigned short)(u >> 16);
}

// Wf fragment-order chunk index for (o, i): 16B chunk = 8 bf16 g-slots.
//   chunk = ((oT*64 + kt)*2 + ks)*64 + lane, o=oT*32+(lane&31), i=kt*4+ks*2+(lane>>5)
// (R7 layout: 1-KB segment per (oT, kt, ks), lane-linear -> DMA-able.)

// Fused prep: blocks [0,256) pack W into fragment order; [256,256+NMB) do
// per-block min/max partials of x (4 independent float4s per thread).
__global__ void __launch_bounds__(256) prep_kernel(const float* __restrict__ coef,
                                                   const float* __restrict__ scale,
                                                   const float* __restrict__ x,
                                                   unsigned short* __restrict__ wf,
                                                   float* __restrict__ part, int n4) {
  const int t = threadIdx.x;
  if (blockIdx.x < 256) {
    int idx = blockIdx.x * 256 + t;        // o*256 + i
    int o = idx >> 8, i = idx & 255;
    float s = scale[idx];
    const float* c = coef + (size_t)idx * 5;
    ushort8 v;
    v[0] = f2bf(c[0] * s); v[1] = f2bf(c[1] * s); v[2] = f2bf(c[2] * s);
    v[3] = f2bf(c[3] * s); v[4] = f2bf(c[4] * s);
    v[5] = 0; v[6] = 0; v[7] = 0;
    int chunk = (((o >> 5) * 64 + (i >> 2)) * 2 + ((i >> 1) & 1)) * 64
                + (i & 1) * 32 + (o & 31);
    *(ushort8*)(wf + (size_t)chunk * 8) = v;
  } else {
    int mb = blockIdx.x - 256;             // [0, NMB)
    const float4* x4 = (const float4*)x;
    // n4 = 2097152 = 4 * NMB * 256 exactly: 4 independent strided loads.
    int i = mb * 256 + t;
    float lmin = 1e30f, lmax = -1e30f;
    #pragma unroll
    for (int k = 0; k < 4; ++k) {
      float4 v = x4[i + k * (NMB * 256)];
      lmin = fminf(lmin, fminf(fminf(v.x, v.y), fminf(v.z, v.w)));
      lmax = fmaxf(lmax, fmaxf(fmaxf(v.x, v.y), fmaxf(v.z, v.w)));
    }
    #pragma unroll
    for (int off = 32; off >= 1; off >>= 1) {
      lmin = fminf(lmin, __shfl_down(lmin, off, 64));
      lmax = fmaxf(lmax, __shfl_down(lmax, off, 64));
    }
    __shared__ float smn[4], smx[4];
    if ((t & 63) == 0) { smn[t >> 6] = lmin; smx[t >> 6] = lmax; }
    __syncthreads();
    if (t == 0) {
      part[2 * mb]     = fminf(fminf(smn[0], smn[1]), fminf(smn[2], smn[3]));
      part[2 * mb + 1] = fmaxf(fmaxf(smx[0], smx[1]), fmaxf(smx[2], smx[3]));
    }
  }
}

// Lean basis octet: ~33 VALU. where(d<1,1-d^3,0) == max(1-d*d*|d|,0) (d>=0
// monotone). eps dropped: sum >= 0.98 always (nearest knot <= 0.25 away).
// bf16 pack by truncation: v_perm_b32 grabs high16 pairs (err <= 2^-8 rel,
// inside the 7.1e-2 budget; measured absmax headroom 4.5x).
__device__ __forceinline__ bf16x8 basisfrag(float xval, float scA, float scB) {
  float xn = fmaf(xval, scA, scB);
  float d0 = xn + 1.0f, d1 = xn + 0.5f, d3 = xn - 0.5f, d4 = xn - 1.0f;
  float b0 = fmaxf(fmaf(d0 * d0, -fabsf(d0), 1.0f), 0.0f);
  float b1 = fmaxf(fmaf(d1 * d1, -fabsf(d1), 1.0f), 0.0f);
  float b2 = fmaxf(fmaf(xn * xn, -fabsf(xn), 1.0f), 0.0f);
  float b3 = fmaxf(fmaf(d3 * d3, -fabsf(d3), 1.0f), 0.0f);
  float b4 = fmaxf(fmaf(d4 * d4, -fabsf(d4), 1.0f), 0.0f);
  float sum = ((b0 + b1) + (b2 + b3)) + b4;
  float inv = __builtin_amdgcn_rcpf(sum);
  b0 *= inv; b1 *= inv; b2 *= inv; b3 *= inv; b4 *= inv;
  frag_u r;
  r.u.x = __builtin_amdgcn_perm(__float_as_uint(b1), __float_as_uint(b0), 0x07060302u);
  r.u.y = __builtin_amdgcn_perm(__float_as_uint(b3), __float_as_uint(b2), 0x07060302u);
  r.u.z = __float_as_uint(b4) >> 16;
  r.u.w = 0u;
  return r.v;
}

__global__ void __launch_bounds__(256, 4) kan_gemm(
    const float* __restrict__ x,            // [32768][256]
    const unsigned short* __restrict__ wf,  // fragment-ordered W, 1 MB
    const float* __restrict__ bias,         // [256]
    const float* __restrict__ part,         // NMB {min,max} partials
    float* __restrict__ out)                // [32768][256]
{
  // B chunk buffers: [buf][ seg = h*8 + ks*4 + oTl ][ lane*16B ] -> 2 x 16 KB.
  // Reused as the 32 KB fp32 combine buffer in the epilogue.
  __shared__ __align__(16) unsigned short Bb[2][8192];
  __shared__ float2 red[4];

  const int t = threadIdx.x;
  const int lane = t & 63;
  const int wm = t >> 6;                     // wave id
  const int sm = wm & 1;                     // M-strip (0,1)
  const int h  = wm >> 1;                    // K-half (0,1)
  const int l31 = lane & 31, lh = lane >> 5;
  const int bRow = blockIdx.x * 64;
  const int bCol = blockIdx.y * 128;
  const int row = bRow + sm * 32 + l31;      // this lane's A row

  // ---- B chunk staging: 16 segments of 1 KB; each wave DMAs 4 (lane-linear).
  //      seg decode: h = seg>>3, ks = (seg>>2)&1, oTl = seg&3; kt = h*32 + c.
  auto stage = [&](int c, int buf) {
    #pragma unroll
    for (int r = 0; r < 4; ++r) {
      int seg = r * 4 + wm;                  // wave-uniform
      int sh = seg >> 3, sks = (seg >> 2) & 1, sot = seg & 3;
      const unsigned short* src = wf +
          ((size_t)(((blockIdx.y * 4 + sot) * 64 + (sh * 32 + c)) * 2 + sks)) * 512
          + (size_t)lane * 8;
      __builtin_amdgcn_global_load_lds(
          (const __attribute__((address_space(1))) unsigned int*)src,
          (__attribute__((address_space(3))) unsigned int*)(&Bb[buf][seg * 512 + lane * 8]),
          16, 0, 0);
    }
  };

  // this wave's x slice: its rows, its K-half (128 floats of the row)
  const float* xrow = x + (size_t)row * IN_SZ + h * 128;

  // prologue: chunk 0 DMA + chunk-0 x load in flight during minmax reduce
  // (the reduce's __syncthreads drains them once -- one-time cost).
  float4 xq = *(const float4*)(xrow);
  stage(0, 0);

  float mn = 1e30f, mx = -1e30f;
  const float2* part2 = (const float2*)part;
  #pragma unroll
  for (int k = 0; k < NMB / 256; ++k) {
    float2 p = part2[k * 256 + t];
    mn = fminf(mn, p.x); mx = fmaxf(mx, p.y);
  }
  #pragma unroll
  for (int off = 32; off >= 1; off >>= 1) {
    mn = fminf(mn, __shfl_down(mn, off, 64));
    mx = fmaxf(mx, __shfl_down(mx, off, 64));
  }
  if (lane == 0) red[wm] = make_float2(mn, mx);
  __syncthreads();
  mn = fminf(fminf(red[0].x, red[1].x), fminf(red[2].x, red[3].x));
  mx = fmaxf(fmaxf(red[0].y, red[1].y), fmaxf(red[2].y, red[3].y));
  const float scA = 2.0f / (mx - mn + EPSF);
  const float scB = -mn * scA - 1.0f;

  floatx16 acc[4] = {};                      // [ni] -> cols ni*32..ni*32+31 (K-half partial)
  bf16x8 bf[8];                              // [ni*2+ks]

  // ---- K loop: 32 chunks x BK=32 (1 kt per chunk); counted vmcnt, no drain ----
  for (int c = 0; c < 32; ++c) {
    const int buf = c & 1;
    float4 xn;

    if (c < 31) {
      // issue next chunk's loads; they stay in flight across the barrier
      xn = *(const float4*)(xrow + (c + 1) * 4);
      stage(c + 1, buf ^ 1);
    }
    __builtin_amdgcn_sched_barrier(0);       // pin issues above the wait
    // newest 5 in flight = {1 x + 4 DMA} for chunk c+1; everything older
    // (chunk c's 4 DMAs, issued a full chunk ago) must retire -> LDS ready.
    if (c < 31) asm volatile("s_waitcnt vmcnt(5)");
    else        asm volatile("s_waitcnt vmcnt(0)");
    __builtin_amdgcn_s_barrier();
    __builtin_amdgcn_sched_barrier(0);       // no ds_read hoists above barrier

    // B fragments for this wave's K-half: seg = h*8 + ks*4 + ni
    #pragma unroll
    for (int q = 0; q < 8; ++q) {            // q = ni*2+ks
      int ni = q >> 1, ks = q & 1;
      bf[q] = *(const bf16x8*)(&Bb[buf][(h * 8 + ks * 4 + ni) * 512 + lane * 8]);
    }

    // A fragments: i = h*128 + c*4 + ks*2 + lh
    float xv0 = lh ? xq.y : xq.x;            // ks=0
    float xv1 = lh ? xq.w : xq.z;            // ks=1
    bf16x8 a0 = basisfrag(xv0, scA, scB);
    bf16x8 a1 = basisfrag(xv1, scA, scB);

    __builtin_amdgcn_s_setprio(1);
    #pragma unroll
    for (int ni = 0; ni < 4; ++ni) {
      acc[ni] = __builtin_amdgcn_mfma_f32_32x32x16_bf16(a0, bf[ni * 2 + 0], acc[ni], 0, 0, 0);
      acc[ni] = __builtin_amdgcn_mfma_f32_32x32x16_bf16(a1, bf[ni * 2 + 1], acc[ni], 0, 0, 0);
    }
    __builtin_amdgcn_s_setprio(0);

    if (c < 31) {
      xq = xn;
      // read-done fence: ds_reads of buf complete before each wave's MFMAs
      // (data deps), which precede this barrier; stage(c+2) into buf comes
      // after the NEXT top barrier.
      __builtin_amdgcn_sched_barrier(0);
      __builtin_amdgcn_s_barrier();
      __builtin_amdgcn_sched_barrier(0);
    }
  }

  // ---- epilogue: balanced split-K combine via LDS (reuses Bb, 32 KB) ----
  // Exchange plan: h=0 exports acc[2],acc[3] (cols 64-127), keeps 0,1;
  //                h=1 exports acc[0],acc[1] (cols 0-63),  keeps 2,3.
  // Region (sm, e): 32 rows x 64 cols fp32, base = (sm*2 + e)*2048 floats.
  // C/D frag: col=lane&31, row=(reg&3)+8*(reg>>2)+4*lh  [m74/m101]
  __syncthreads();                           // all MFMAs done before Bb reuse
  float* Cb = (float*)Bb;
  {
    int eo = h ? 0 : 2;                      // exported ni base
    int e  = h ? 0 : 1;                      // exported col-half
    float* base = Cb + (sm * 2 + e) * 2048;
    #pragma unroll
    for (int ni2 = 0; ni2 < 2; ++ni2) {
      #pragma unroll
      for (int reg = 0; reg < 16; ++reg) {
        int r = 4 * lh + (reg & 3) + 8 * (reg >> 2);
        base[r * 64 + ni2 * 32 + l31] = acc[eo + ni2][reg];
      }
    }
  }
  __syncthreads();
  {
    int ko = h ? 2 : 0;                      // kept ni base (cols h*64..h*64+63)
    const float* base = Cb + (sm * 2 + h) * 2048;  // partner's export for my cols
    #pragma unroll
    for (int ni2 = 0; ni2 < 2; ++ni2) {
      int o = bCol + h * 64 + ni2 * 32 + l31;
      float bs = bias[o];
      #pragma unroll
      for (int reg = 0; reg < 16; ++reg) {
        int r = 4 * lh + (reg & 3) + 8 * (reg >> 2);
        float v = acc[ko + ni2][reg] + base[r * 64 + ni2 * 32 + l31] + bs;
        out[(size_t)(bRow + sm * 32 + r) * OUT_SZ + o] = v;
      }
    }
  }
}

extern "C" void kernel_launch(void* const* d_in, const int* in_sizes, int n_in,
                              void* d_out, int out_size, void* d_ws, size_t ws_size,
                              hipStream_t stream) {
  const float* x     = (const float*)d_in[0];
  // d_in[1] = grid: linspace(-1,1,5), hardcoded
  const float* coef  = (const float*)d_in[2];
  const float* scale = (const float*)d_in[3];
  const float* bias  = (const float*)d_in[4];
  float* out = (float*)d_out;

  // ws: [0..NMB*8) minmax partials (NMB float2), [16384..) Wf (1 MB)
  size_t need = 16384 + (size_t)OUT_SZ * IN_SZ * 8 * 2;
  if (ws_size < need) return;

  float* part = (float*)d_ws;
  unsigned short* wf = (unsigned short*)((char*)d_ws + 16384);

  prep_kernel<<<256 + NMB, 256, 0, stream>>>(coef, scale, x, wf, part,
                                             (B_SZ * IN_SZ) / 4);
  dim3 g(B_SZ / 64, OUT_SZ / 128);
  kan_gemm<<<g, 256, 0, stream>>>(x, wf, bias, part, out);
}

// Round 7
// 135.425 us; speedup vs baseline: 1.0734x; 1.0367x over previous
//
#include <hip/hip_runtime.h>
#include <stdint.h>

// KAN layer as bf16 MFMA GEMM: out = phi @ W^T + bias
//   phi[b, i*8+g] = normalized cubic-bump basis (g<5; 3 zero-pad cols)
// M=32768, N=256, K=2048.
// R14: mrep=2 + dupN=2 + splitK=2 -> 2 waves/SIMD (R7's proven occupancy)
//   with HALF the LDS-read floor. Verified identity: waves/SIMD =
//   splitK*dupN/mrep; pipe floors per CU: MFMA 13.7us (fixed), LDS-reads
//   20.5/mrep us, basis-VALU ~3.5*dupN us/SIMD. R7 = (1,2,1): LDS-bound
//   20.5 + VALU 20 + MFMA 13.7 near-serial = 52.7. This config (2,2,2):
//   LDS 10.2, VALU same, MFMA 13.7 -> MFMA-dominant; 16 MFMA per 8
//   ds_read batch per kt gives 2x intra-wave latency cover.
//   Wave = 64 rows (2 strips) x 128 cols, acc[2][4] = 128 VGPR; block =
//   4 waves = 2 M-pos x 2 K-halves = 128x128 out; grid (256,2) = 512
//   blocks = 2 blocks/CU; BK=64/half, 16 chunks x 2 barriers (R7 cadence);
//   LDS 2 x 32 KB (both halves staged per chunk). Split-K combine = R13's
//   verified LDS-exchange epilogue scaled to 64x64 regions (reuses Bb).
//   Single-buffered B-frags (no reg dbuf) to fit 256-VGPR/2-wave budget.
//   Sync: clobber-free counted vmcnt(12) {4 x-float4 + 8 DMA in flight},
//   never drain in main loop (R10/12/13-verified pattern).

#define B_SZ   32768
#define IN_SZ  256
#define OUT_SZ 256
#define EPSF   1e-8f
#define NMB    2048   // minmax partial blocks

typedef __bf16 bf16x8 __attribute__((ext_vector_type(8)));
typedef unsigned short ushort8 __attribute__((ext_vector_type(8)));
typedef float floatx16 __attribute__((ext_vector_type(16)));

union frag_u { uint4 u; bf16x8 v; };

__device__ __forceinline__ unsigned short f2bf(float f) {
  unsigned u = __float_as_uint(f);
  u += 0x7FFFu + ((u >> 16) & 1u);
  return (unsigned short)(u >> 16);
}

// Wf fragment-order chunk index for (o, i): 16B chunk = 8 bf16 g-slots.
//   chunk = ((oT*64 + kt)*2 + ks)*64 + lane, o=oT*32+(lane&31), i=kt*4+ks*2+(lane>>5)
// (R7 layout: 1-KB segment per (oT, kt, ks), lane-linear -> DMA-able.)

// Fused prep: blocks [0,256) pack W into fragment order; [256,256+NMB) do
// per-block min/max partials of x (4 independent float4s per thread).
__global__ void __launch_bounds__(256) prep_kernel(const float* __restrict__ coef,
                                                   const float* __restrict__ scale,
                                                   const float* __restrict__ x,
                                                   unsigned short* __restrict__ wf,
                                                   float* __restrict__ part, int n4) {
  const int t = threadIdx.x;
  if (blockIdx.x < 256) {
    int idx = blockIdx.x * 256 + t;        // o*256 + i
    int o = idx >> 8, i = idx & 255;
    float s = scale[idx];
    const float* c = coef + (size_t)idx * 5;
    ushort8 v;
    v[0] = f2bf(c[0] * s); v[1] = f2bf(c[1] * s); v[2] = f2bf(c[2] * s);
    v[3] = f2bf(c[3] * s); v[4] = f2bf(c[4] * s);
    v[5] = 0; v[6] = 0; v[7] = 0;
    int chunk = (((o >> 5) * 64 + (i >> 2)) * 2 + ((i >> 1) & 1)) * 64
                + (i & 1) * 32 + (o & 31);
    *(ushort8*)(wf + (size_t)chunk * 8) = v;
  } else {
    int mb = blockIdx.x - 256;             // [0, NMB)
    const float4* x4 = (const float4*)x;
    // n4 = 2097152 = 4 * NMB * 256 exactly: 4 independent strided loads.
    int i = mb * 256 + t;
    float lmin = 1e30f, lmax = -1e30f;
    #pragma unroll
    for (int k = 0; k < 4; ++k) {
      float4 v = x4[i + k * (NMB * 256)];
      lmin = fminf(lmin, fminf(fminf(v.x, v.y), fminf(v.z, v.w)));
      lmax = fmaxf(lmax, fmaxf(fmaxf(v.x, v.y), fmaxf(v.z, v.w)));
    }
    #pragma unroll
    for (int off = 32; off >= 1; off >>= 1) {
      lmin = fminf(lmin, __shfl_down(lmin, off, 64));
      lmax = fmaxf(lmax, __shfl_down(lmax, off, 64));
    }
    __shared__ float smn[4], smx[4];
    if ((t & 63) == 0) { smn[t >> 6] = lmin; smx[t >> 6] = lmax; }
    __syncthreads();
    if (t == 0) {
      part[2 * mb]     = fminf(fminf(smn[0], smn[1]), fminf(smn[2], smn[3]));
      part[2 * mb + 1] = fmaxf(fmaxf(smx[0], smx[1]), fmaxf(smx[2], smx[3]));
    }
  }
}

// Lean basis octet: ~33 VALU. where(d<1,1-d^3,0) == max(1-d*d*|d|,0) (d>=0
// monotone). eps dropped: sum >= 0.98 always (nearest knot <= 0.25 away).
// bf16 pack by truncation: v_perm_b32 grabs high16 pairs (err <= 2^-8 rel,
// inside the 7.1e-2 budget; measured absmax headroom 4.5x).
__device__ __forceinline__ bf16x8 basisfrag(float xval, float scA, float scB) {
  float xn = fmaf(xval, scA, scB);
  float d0 = xn + 1.0f, d1 = xn + 0.5f, d3 = xn - 0.5f, d4 = xn - 1.0f;
  float b0 = fmaxf(fmaf(d0 * d0, -fabsf(d0), 1.0f), 0.0f);
  float b1 = fmaxf(fmaf(d1 * d1, -fabsf(d1), 1.0f), 0.0f);
  float b2 = fmaxf(fmaf(xn * xn, -fabsf(xn), 1.0f), 0.0f);
  float b3 = fmaxf(fmaf(d3 * d3, -fabsf(d3), 1.0f), 0.0f);
  float b4 = fmaxf(fmaf(d4 * d4, -fabsf(d4), 1.0f), 0.0f);
  float sum = ((b0 + b1) + (b2 + b3)) + b4;
  float inv = __builtin_amdgcn_rcpf(sum);
  b0 *= inv; b1 *= inv; b2 *= inv; b3 *= inv; b4 *= inv;
  frag_u r;
  r.u.x = __builtin_amdgcn_perm(__float_as_uint(b1), __float_as_uint(b0), 0x07060302u);
  r.u.y = __builtin_amdgcn_perm(__float_as_uint(b3), __float_as_uint(b2), 0x07060302u);
  r.u.z = __float_as_uint(b4) >> 16;
  r.u.w = 0u;
  return r.v;
}

__global__ void __launch_bounds__(256, 2) kan_gemm(
    const float* __restrict__ x,            // [32768][256]
    const unsigned short* __restrict__ wf,  // fragment-ordered W, 1 MB
    const float* __restrict__ bias,         // [256]
    const float* __restrict__ part,         // NMB {min,max} partials
    float* __restrict__ out)                // [32768][256]
{
  // B chunk buffers: [buf][ seg = h*16 + ktr*8 + ks*4 + ni ][ lane*16B ]
  //   -> 2 x 32 KB. Reused as the 64 KB fp32 combine buffer in epilogue.
  __shared__ __align__(16) unsigned short Bb[2][16384];
  __shared__ float2 red[4];

  const int t = threadIdx.x;
  const int lane = t & 63;
  const int wm = t >> 6;                     // wave id
  const int sm = wm & 1;                     // M-position (0,1)
  const int h  = wm >> 1;                    // K-half (0,1)
  const int l31 = lane & 31, lh = lane >> 5;
  const int bRow = blockIdx.x * 128;
  const int bCol = blockIdx.y * 128;

  // ---- B chunk staging: 32 segments of 1 KB; each wave DMAs 8 (lane-linear).
  //      seg decode: sh = s>>4, sktr = (s>>3)&1, sks = (s>>2)&1, sni = s&3;
  //      global kt = sh*32 + c*2 + sktr.
  auto stage = [&](int c, int buf) {
    #pragma unroll
    for (int r = 0; r < 8; ++r) {
      int s = r * 4 + wm;                    // wave-uniform
      int sh = s >> 4, sktr = (s >> 3) & 1, sks = (s >> 2) & 1, sni = s & 3;
      const unsigned short* src = wf +
          ((size_t)(((blockIdx.y * 4 + sni) * 64 + (sh * 32 + c * 2 + sktr)) * 2 + sks)) * 512
          + (size_t)lane * 8;
      __builtin_amdgcn_global_load_lds(
          (const __attribute__((address_space(1))) unsigned int*)src,
          (__attribute__((address_space(3))) unsigned int*)(&Bb[buf][s * 512 + lane * 8]),
          16, 0, 0);
    }
  };

  // this wave's x slices: strip rows, its K-half (128 floats of each row)
  const float* xrow0 = x + (size_t)(bRow + sm * 64 + l31) * IN_SZ + h * 128;
  const float* xrow1 = xrow0 + 32 * IN_SZ;

  // prologue: chunk 0 DMA + chunk-0 x loads in flight during minmax reduce
  // (the reduce's __syncthreads drains them once -- one-time cost).
  stage(0, 0);
  float4 xq0[2], xq1[2], xqn0[2], xqn1[2];   // [ktr]
  #pragma unroll
  for (int j = 0; j < 2; ++j) {
    xq0[j] = *(const float4*)(xrow0 + j * 4);
    xq1[j] = *(const float4*)(xrow1 + j * 4);
  }

  float mn = 1e30f, mx = -1e30f;
  const float2* part2 = (const float2*)part;
  #pragma unroll
  for (int k = 0; k < NMB / 256; ++k) {
    float2 p = part2[k * 256 + t];
    mn = fminf(mn, p.x); mx = fmaxf(mx, p.y);
  }
  #pragma unroll
  for (int off = 32; off >= 1; off >>= 1) {
    mn = fminf(mn, __shfl_down(mn, off, 64));
    mx = fmaxf(mx, __shfl_down(mx, off, 64));
  }
  if (lane == 0) red[wm] = make_float2(mn, mx);
  __syncthreads();
  mn = fminf(fminf(red[0].x, red[1].x), fminf(red[2].x, red[3].x));
  mx = fmaxf(fmaxf(red[0].y, red[1].y), fmaxf(red[2].y, red[3].y));
  const float scA = 2.0f / (mx - mn + EPSF);
  const float scB = -mn * scA - 1.0f;

  floatx16 acc0[4] = {}, acc1[4] = {};       // [strip][ni], K-half partials
  bf16x8 bf[8];                              // [ks*4 + ni], single-buffered

  // ---- K loop: 16 chunks x BK=64 (2 kt per chunk); counted vmcnt, no drain ----
  for (int c = 0; c < 16; ++c) {
    const int buf = c & 1;

    if (c < 15) {
      // issue next chunk's loads; they stay in flight across the barrier
      #pragma unroll
      for (int j = 0; j < 2; ++j) {
        xqn0[j] = *(const float4*)(xrow0 + (c + 1) * 8 + j * 4);
        xqn1[j] = *(const float4*)(xrow1 + (c + 1) * 8 + j * 4);
      }
      stage(c + 1, buf ^ 1);
    }
    __builtin_amdgcn_sched_barrier(0);       // pin issues above the wait
    // newest 12 in flight = {4 x + 8 DMA} for chunk c+1; everything older
    // (chunk c's 12, issued a full chunk ago) must retire -> LDS ready.
    if (c < 15) asm volatile("s_waitcnt vmcnt(12)");
    else        asm volatile("s_waitcnt vmcnt(0)");
    __builtin_amdgcn_s_barrier();
    __builtin_amdgcn_sched_barrier(0);       // no ds_read hoists above barrier

    #pragma unroll
    for (int ktr = 0; ktr < 2; ++ktr) {
      // B fragments for this wave's K-half: seg = h*16 + ktr*8 + q
      #pragma unroll
      for (int q = 0; q < 8; ++q)
        bf[q] = *(const bf16x8*)(&Bb[buf][(h * 16 + ktr * 8 + q) * 512 + lane * 8]);

      // A fragments: i = h*128 + c*8 + ktr*4 + ks*2 + lh
      float4 q0 = xq0[ktr], q1 = xq1[ktr];
      bf16x8 a00 = basisfrag(lh ? q0.y : q0.x, scA, scB);  // strip0 ks=0
      bf16x8 a01 = basisfrag(lh ? q0.w : q0.z, scA, scB);  // strip0 ks=1
      bf16x8 a10 = basisfrag(lh ? q1.y : q1.x, scA, scB);  // strip1 ks=0
      bf16x8 a11 = basisfrag(lh ? q1.w : q1.z, scA, scB);  // strip1 ks=1

      __builtin_amdgcn_s_setprio(1);
      #pragma unroll
      for (int ni = 0; ni < 4; ++ni) {       // ks=0: bf[0..3]
        acc0[ni] = __builtin_amdgcn_mfma_f32_32x32x16_bf16(a00, bf[ni], acc0[ni], 0, 0, 0);
        acc1[ni] = __builtin_amdgcn_mfma_f32_32x32x16_bf16(a10, bf[ni], acc1[ni], 0, 0, 0);
      }
      #pragma unroll
      for (int ni = 0; ni < 4; ++ni) {       // ks=1: bf[4..7]
        acc0[ni] = __builtin_amdgcn_mfma_f32_32x32x16_bf16(a01, bf[4 + ni], acc0[ni], 0, 0, 0);
        acc1[ni] = __builtin_amdgcn_mfma_f32_32x32x16_bf16(a11, bf[4 + ni], acc1[ni], 0, 0, 0);
      }
      __builtin_amdgcn_s_setprio(0);
    }

    if (c < 15) {
      #pragma unroll
      for (int j = 0; j < 2; ++j) {
        xq0[j] = xqn0[j]; xq1[j] = xqn1[j];
      }
      // read-done fence: all reads of buf precede this barrier; stage(c+2)
      // into buf comes after it (in iter c+1, before the top barrier).
      __builtin_amdgcn_sched_barrier(0);
      __builtin_amdgcn_s_barrier();
      __builtin_amdgcn_sched_barrier(0);
    }
  }

  // ---- epilogue: split-K combine via LDS (reuses Bb, 64 KB) ----
  // Region (sm, e): 64 rows x 64 cols fp32 = 16 KB at (sm*2+e)*4096 floats;
  // region e holds cols e*64..e*64+63 of M-block sm.
  // h=0 exports e=1 (ni 2,3), keeps cols 0-63; h=1 exports e=0 (ni 0,1).
  // C/D frag: col=lane&31, row=(reg&3)+8*(reg>>2)+4*lh  [m74/m101]
  __syncthreads();                           // all LDS reads done before reuse
  float* Cb = (float*)Bb;
  {
    int eo = h ? 0 : 2;                      // exported ni base
    int e  = h ? 0 : 1;                      // exported col-half
    float* base = Cb + (sm * 2 + e) * 4096;
    #pragma unroll
    for (int ni2 = 0; ni2 < 2; ++ni2) {
      #pragma unroll
      for (int reg = 0; reg < 16; ++reg) {
        int r = 4 * lh + (reg & 3) + 8 * (reg >> 2);
        base[r * 64 + ni2 * 32 + l31]        = acc0[eo + ni2][reg];
        base[(r + 32) * 64 + ni2 * 32 + l31] = acc1[eo + ni2][reg];
      }
    }
  }
  __syncthreads();
  {
    int ko = h ? 2 : 0;                      // kept ni base (cols h*64 + ...)
    const float* base = Cb + (sm * 2 + h) * 4096;  // partner's export, my cols
    #pragma unroll
    for (int ni2 = 0; ni2 < 2; ++ni2) {
      int o = bCol + h * 64 + ni2 * 32 + l31;
      float bs = bias[o];
      #pragma unroll
      for (int reg = 0; reg < 16; ++reg) {
        int r = 4 * lh + (reg & 3) + 8 * (reg >> 2);
        float v0 = acc0[ko + ni2][reg] + base[r * 64 + ni2 * 32 + l31] + bs;
        float v1 = acc1[ko + ni2][reg] + base[(r + 32) * 64 + ni2 * 32 + l31] + bs;
        out[(size_t)(bRow + sm * 64 + r) * OUT_SZ + o] = v0;
        out[(size_t)(bRow + sm * 64 + r + 32) * OUT_SZ + o] = v1;
      }
    }
  }
}

extern "C" void kernel_launch(void* const* d_in, const int* in_sizes, int n_in,
                              void* d_out, int out_size, void* d_ws, size_t ws_size,
                              hipStream_t stream) {
  const float* x     = (const float*)d_in[0];
  // d_in[1] = grid: linspace(-1,1,5), hardcoded
  const float* coef  = (const float*)d_in[2];
  const float* scale = (const float*)d_in[3];
  const float* bias  = (const float*)d_in[4];
  float* out = (float*)d_out;

  // ws: [0..NMB*8) minmax partials (NMB float2), [16384..) Wf (1 MB)
  size_t need = 16384 + (size_t)OUT_SZ * IN_SZ * 8 * 2;
  if (ws_size < need) return;

  float* part = (float*)d_ws;
  unsigned short* wf = (unsigned short*)((char*)d_ws + 16384);

  prep_kernel<<<256 + NMB, 256, 0, stream>>>(coef, scale, x, wf, part,
                                             (B_SZ * IN_SZ) / 4);
  dim3 g(B_SZ / 128, OUT_SZ / 128);
  kan_gemm<<<g, 256, 0, stream>>>(x, wf, bias, part, out);
}

// Round 8
// 132.362 us; speedup vs baseline: 1.0982x; 1.0231x over previous
//
#include <hip/hip_runtime.h>
#include <stdint.h>

// KAN layer as bf16 MFMA GEMM: out = phi @ W^T + bias
//   phi[b, i*8+g] = normalized cubic-bump basis (g<5; 3 zero-pad cols)
// M=32768, N=256, K=2048 (16 chunks x BK=128, 4 ktr of K=32).
// R15 = R7 (best-known, 52.7us) + two minimal deltas:
//   (1) basisfrag HOIST: all 8 A-fragments computed at chunk top (dep only
//       on xq), removing the ~260cy VALU+rcp chain from between every
//       ds_read batch and its MFMAs. Per-ktr body becomes pure ds+MFMA ->
//       the 2 resident waves/SIMD can dovetail (VALU burst of one under
//       MFMA phase of the other, m114), and ds latency hides under the
//       burst within a wave.
//   (2) grid transpose (1-D 512 blocks, by=bid&1): the 2 blocks sharing
//       x-rows are dispatch-adjacent -> same XCD -> x re-read L2-local.
// Evidence basis: R8 counted-vmcnt EXACTLY neutral (drain already
//   amortized at prefetch-distance-1); R13/R14 killed the LDS-floor and
//   splitK hypotheses (halving LDS reads made it slower); R10/11/12
//   bracketed occupancy. Remaining suspect = VALU on the per-ktr chain.

#define B_SZ   32768
#define IN_SZ  256
#define OUT_SZ 256
#define EPSF   1e-8f
#define NMB    2048   // minmax partial blocks

typedef __bf16 bf16x8 __attribute__((ext_vector_type(8)));
typedef unsigned short ushort8 __attribute__((ext_vector_type(8)));
typedef float floatx16 __attribute__((ext_vector_type(16)));

union frag_u { uint4 u; bf16x8 v; };

__device__ __forceinline__ unsigned short f2bf(float f) {
  unsigned u = __float_as_uint(f);
  u += 0x7FFFu + ((u >> 16) & 1u);
  return (unsigned short)(u >> 16);
}

// Wf fragment-order chunk index for (o, i): 16B chunk = 8 bf16 g-slots.
//   chunk = ((oT*64 + kt)*2 + ks)*64 + lane, o=oT*32+(lane&31), i=kt*4+ks*2+(lane>>5)

// Fused prep: blocks [0,256) pack W into fragment order; [256,256+NMB) do
// per-block min/max partials of x (4 independent float4s per thread).
__global__ void __launch_bounds__(256) prep_kernel(const float* __restrict__ coef,
                                                   const float* __restrict__ scale,
                                                   const float* __restrict__ x,
                                                   unsigned short* __restrict__ wf,
                                                   float* __restrict__ part, int n4) {
  const int t = threadIdx.x;
  if (blockIdx.x < 256) {
    int idx = blockIdx.x * 256 + t;        // o*256 + i
    int o = idx >> 8, i = idx & 255;
    float s = scale[idx];
    const float* c = coef + (size_t)idx * 5;
    ushort8 v;
    v[0] = f2bf(c[0] * s); v[1] = f2bf(c[1] * s); v[2] = f2bf(c[2] * s);
    v[3] = f2bf(c[3] * s); v[4] = f2bf(c[4] * s);
    v[5] = 0; v[6] = 0; v[7] = 0;
    int chunk = (((o >> 5) * 64 + (i >> 2)) * 2 + ((i >> 1) & 1)) * 64
                + (i & 1) * 32 + (o & 31);
    *(ushort8*)(wf + (size_t)chunk * 8) = v;
  } else {
    int mb = blockIdx.x - 256;             // [0, NMB)
    const float4* x4 = (const float4*)x;
    // n4 = 2097152 = 4 * NMB * 256 exactly: 4 independent strided loads.
    int i = mb * 256 + t;
    float lmin = 1e30f, lmax = -1e30f;
    #pragma unroll
    for (int k = 0; k < 4; ++k) {
      float4 v = x4[i + k * (NMB * 256)];
      lmin = fminf(lmin, fminf(fminf(v.x, v.y), fminf(v.z, v.w)));
      lmax = fmaxf(lmax, fmaxf(fmaxf(v.x, v.y), fmaxf(v.z, v.w)));
    }
    #pragma unroll
    for (int off = 32; off >= 1; off >>= 1) {
      lmin = fminf(lmin, __shfl_down(lmin, off, 64));
      lmax = fmaxf(lmax, __shfl_down(lmax, off, 64));
    }
    __shared__ float smn[4], smx[4];
    if ((t & 63) == 0) { smn[t >> 6] = lmin; smx[t >> 6] = lmax; }
    __syncthreads();
    if (t == 0) {
      part[2 * mb]     = fminf(fminf(smn[0], smn[1]), fminf(smn[2], smn[3]));
      part[2 * mb + 1] = fmaxf(fmaxf(smx[0], smx[1]), fmaxf(smx[2], smx[3]));
    }
  }
}

// Lean basis octet: ~33 VALU. where(d<1,1-d^3,0) == max(1-d*d*|d|,0) (d>=0
// monotone). eps dropped: sum >= 0.98 always (nearest knot <= 0.25 away).
// bf16 pack by truncation: v_perm_b32 grabs high16 pairs (err <= 2^-8 rel,
// inside the 7.1e-2 budget; measured absmax headroom 4.5x).
__device__ __forceinline__ bf16x8 basisfrag(float xval, float scA, float scB) {
  float xn = fmaf(xval, scA, scB);
  float d0 = xn + 1.0f, d1 = xn + 0.5f, d3 = xn - 0.5f, d4 = xn - 1.0f;
  float b0 = fmaxf(fmaf(d0 * d0, -fabsf(d0), 1.0f), 0.0f);
  float b1 = fmaxf(fmaf(d1 * d1, -fabsf(d1), 1.0f), 0.0f);
  float b2 = fmaxf(fmaf(xn * xn, -fabsf(xn), 1.0f), 0.0f);
  float b3 = fmaxf(fmaf(d3 * d3, -fabsf(d3), 1.0f), 0.0f);
  float b4 = fmaxf(fmaf(d4 * d4, -fabsf(d4), 1.0f), 0.0f);
  float sum = ((b0 + b1) + (b2 + b3)) + b4;
  float inv = __builtin_amdgcn_rcpf(sum);
  b0 *= inv; b1 *= inv; b2 *= inv; b3 *= inv; b4 *= inv;
  frag_u r;
  r.u.x = __builtin_amdgcn_perm(__float_as_uint(b1), __float_as_uint(b0), 0x07060302u);
  r.u.y = __builtin_amdgcn_perm(__float_as_uint(b3), __float_as_uint(b2), 0x07060302u);
  r.u.z = __float_as_uint(b4) >> 16;
  r.u.w = 0u;
  return r.v;
}

__global__ void __launch_bounds__(256, 2) kan_gemm(
    const float* __restrict__ x,            // [32768][256]
    const unsigned short* __restrict__ wf,  // fragment-ordered W, 1 MB
    const float* __restrict__ bias,         // [256]
    const float* __restrict__ part,         // NMB {min,max} partials
    float* __restrict__ out)                // [32768][256]
{
  // B chunk buffers: [buf][ (ni*4+ktr)*2+ks ][ lane*16B ]  -> 2 x 32 KB
  __shared__ __align__(16) unsigned short Bb[2][16384];
  __shared__ float2 red[4];

  const int t = threadIdx.x;
  const int lane = t & 63;
  const int wm = t >> 6;                     // 4 waves stacked in m
  const int l31 = lane & 31, lh = lane >> 5;
  // grid transpose: 1-D 512 blocks; the 2 N-halves of the same M-tile are
  // dispatch-adjacent -> same XCD -> shared x-rows stay L2-local.
  const int by = blockIdx.x & 1;
  const int bx = blockIdx.x >> 1;
  const int bRow = bx * 128;
  const int bCol = by * 128;
  const int row = bRow + wm * 32 + l31;      // this lane's A row

  // ---- B chunk staging: 32 segments of 1 KB; each wave DMAs 8 (lane-linear) ----
  auto stage = [&](int c, int buf) {
    #pragma unroll
    for (int r = 0; r < 8; ++r) {
      int idx = r * 4 + wm;                  // wave-uniform
      const unsigned short* src = wf +
          ((size_t)(((by * 4 + (idx >> 3)) * 64 + (c * 4 + ((idx >> 1) & 3))) * 2
                    + (idx & 1))) * 512 + (size_t)lane * 8;
      __builtin_amdgcn_global_load_lds(
          (const __attribute__((address_space(1))) unsigned int*)src,
          (__attribute__((address_space(3))) unsigned int*)(&Bb[buf][idx * 512 + lane * 8]),
          16, 0, 0);
    }
  };

  const float* xrow = x + (size_t)row * IN_SZ;

  // prologue: chunk 0 DMA + group-0 x loads in flight during minmax reduce
  stage(0, 0);
  float4 xq[4], xqn[4];
  #pragma unroll
  for (int g = 0; g < 4; ++g) xq[g] = *(const float4*)(xrow + g * 4);

  float mn = 1e30f, mx = -1e30f;
  const float2* part2 = (const float2*)part;
  #pragma unroll
  for (int k = 0; k < NMB / 256; ++k) {
    float2 p = part2[k * 256 + t];
    mn = fminf(mn, p.x); mx = fmaxf(mx, p.y);
  }
  #pragma unroll
  for (int off = 32; off >= 1; off >>= 1) {
    mn = fminf(mn, __shfl_down(mn, off, 64));
    mx = fmaxf(mx, __shfl_down(mx, off, 64));
  }
  if (lane == 0) red[wm] = make_float2(mn, mx);
  __syncthreads();
  mn = fminf(fminf(red[0].x, red[1].x), fminf(red[2].x, red[3].x));
  mx = fmaxf(fmaxf(red[0].y, red[1].y), fmaxf(red[2].y, red[3].y));
  const float scA = 2.0f / (mx - mn + EPSF);
  const float scB = -mn * scA - 1.0f;

  floatx16 acc[4] = {};
  bf16x8 br[2][8];                           // [ktr parity][ni*2+ks]

  auto ldsB = [&](int ktr, int buf, bf16x8* dst) {
    #pragma unroll
    for (int q = 0; q < 8; ++q) {            // q = ni*2+ks
      int ni = q >> 1, ks = q & 1;
      dst[q] = *(const bf16x8*)(&Bb[buf][((ni * 4 + ktr) * 2 + ks) * 512 + lane * 8]);
    }
  };

  // ---- K loop: 16 chunks; ONE barrier per chunk (R7 cadence) ----
  for (int c = 0; c < 16; ++c) {
    const int buf = c & 1;

    __syncthreads();   // drain == chunk-c DMA ready (issued 1 chunk ago);
                       // also fences prev-buf LDS reads.

    if (c < 15) {      // next chunk's DMA + x loads in flight for a full chunk
      stage(c + 1, buf ^ 1);
      #pragma unroll
      for (int g = 0; g < 4; ++g)
        xqn[g] = *(const float4*)(xrow + (c + 1) * 16 + g * 4);
    }

    ldsB(0, buf, br[0]);                     // chunk-leading fragment load

    // hoisted A-fragment burst: depends only on xq -- off the ktr chain.
    bf16x8 af0[4], af1[4];
    #pragma unroll
    for (int ktr = 0; ktr < 4; ++ktr) {
      af0[ktr] = basisfrag(lh ? xq[ktr].y : xq[ktr].x, scA, scB);  // ks=0
      af1[ktr] = basisfrag(lh ? xq[ktr].w : xq[ktr].z, scA, scB);  // ks=1
    }

    #pragma unroll
    for (int ktr = 0; ktr < 4; ++ktr) {
      if (ktr < 3) ldsB(ktr + 1, buf, br[(ktr + 1) & 1]);  // prefetch next ktr
      bf16x8* B = br[ktr & 1];
      #pragma unroll
      for (int ni = 0; ni < 4; ++ni)
        acc[ni] = __builtin_amdgcn_mfma_f32_32x32x16_bf16(af0[ktr], B[ni * 2 + 0], acc[ni], 0, 0, 0);
      #pragma unroll
      for (int ni = 0; ni < 4; ++ni)
        acc[ni] = __builtin_amdgcn_mfma_f32_32x32x16_bf16(af1[ktr], B[ni * 2 + 1], acc[ni], 0, 0, 0);
    }

    if (c < 15) {
      #pragma unroll
      for (int g = 0; g < 4; ++g) xq[g] = xqn[g];
    }
  }

  // epilogue: C/D col=lane&31, row=(reg&3)+8*(reg>>2)+4*(lane>>5) [m74/m101]
  #pragma unroll
  for (int ni = 0; ni < 4; ++ni) {
    int o = bCol + ni * 32 + l31;
    float bs = bias[o];
    int rb = bRow + wm * 32 + 4 * lh;
    #pragma unroll
    for (int reg = 0; reg < 16; ++reg) {
      int r = rb + (reg & 3) + 8 * (reg >> 2);
      out[(size_t)r * OUT_SZ + o] = acc[ni][reg] + bs;
    }
  }
}

extern "C" void kernel_launch(void* const* d_in, const int* in_sizes, int n_in,
                              void* d_out, int out_size, void* d_ws, size_t ws_size,
                              hipStream_t stream) {
  const float* x     = (const float*)d_in[0];
  // d_in[1] = grid: linspace(-1,1,5), hardcoded
  const float* coef  = (const float*)d_in[2];
  const float* scale = (const float*)d_in[3];
  const float* bias  = (const float*)d_in[4];
  float* out = (float*)d_out;

  // ws: [0..NMB*8) minmax partials (NMB float2), [16384..) Wf (1 MB)
  size_t need = 16384 + (size_t)OUT_SZ * IN_SZ * 8 * 2;
  if (ws_size < need) return;

  float* part = (float*)d_ws;
  unsigned short* wf = (unsigned short*)((char*)d_ws + 16384);

  prep_kernel<<<256 + NMB, 256, 0, stream>>>(coef, scale, x, wf, part,
                                             (B_SZ * IN_SZ) / 4);
  kan_gemm<<<512, 256, 0, stream>>>(x, wf, bias, part, out);
}

// Round 9
// 123.372 us; speedup vs baseline: 1.1783x; 1.0729x over previous
//
#include <hip/hip_runtime.h>
#include <stdint.h>

// KAN layer as bf16 MFMA GEMM, 5-DENSE K-packing: out = phi @ W^T + bias
//   phi[b, i*5+g] = normalized cubic-bump basis, K = 1280 (was 2048 with
//   3 zero-pad g-slots per input = 37.5% wasted MFMA/LDS/fetch).
// R16 = R7 skeleton (1 barrier/chunk, 52.7us, proven local optimum over
//   8 schedule/occupancy/tiling experiments) with the padded workload
//   removed. Key design: per K16 tile kt, lane-half lh gets dense values
//   [kt*8,kt*8+8) of inputs [c*16+lh*8, +8) -> both halves run IDENTICAL
//   code on lh-selected x (8 cndmask, no divergence); 8 quintets/lane/chunk
//   (VALU ~flat vs R7); per-kt A-frag assembly = 2-3 compile-time v_perm
//   (5-phase cycle). W pre-packed to match by prep (k->(i,g) map is ours).
//   BK=80 (16 inputs/chunk, x loads = 4 aligned float4 as R7), 16 chunks,
//   5 kt x 4 MFMA; LDS 2x20KB. Floors: MFMA 13.7->8.6us, LDS 20.5->12.8,
//   wf 2->1.25MB. Grid reverted to dim3(256,2) (R15: transpose broke the
//   accidental same-XCD x-pairing; FETCH 20.5->35MB).

#define B_SZ   32768
#define IN_SZ  256
#define OUT_SZ 256
#define EPSF   1e-8f
#define NMB    2048   // minmax partial blocks

typedef __bf16 bf16x8 __attribute__((ext_vector_type(8)));
typedef unsigned short ushort8 __attribute__((ext_vector_type(8)));
typedef float floatx16 __attribute__((ext_vector_type(16)));

union frag_u { uint4 u; bf16x8 v; };

// v_perm selectors (dst = (lo, hi) bf16 pair):
//   PKHH: lo = src1.hi16, hi = src0.hi16  (pack two f32 -> bf16x2, trunc)
//   PKLL: lo = src1.lo16, hi = src0.lo16
//   PKHL: lo = src1.hi16, hi = src0.lo16
#define PKHH 0x07060302u
#define PKLL 0x05040100u
#define PKHL 0x05040302u

__device__ __forceinline__ unsigned short f2bf(float f) {
  unsigned u = __float_as_uint(f);
  u += 0x7FFFu + ((u >> 16) & 1u);
  return (unsigned short)(u >> 16);
}

// Dense-pack layout: value v in chunk c = lh*40 + kt*8 + j  (j=0..7),
//   (i_local, g) = (v/5, v%5), i = c*16 + i_local. Segment (c, oTg, kt) =
//   1 KB lane-linear: lane l = lh*32 + (o&31) holds its 8 bf16 k-slots.
//   640 segments = 640 KB.

// Fused prep: blocks [0,160) pack W 5-dense; [160,160+NMB) min/max partials.
__global__ void __launch_bounds__(256) prep_kernel(const float* __restrict__ coef,
                                                   const float* __restrict__ scale,
                                                   const float* __restrict__ x,
                                                   unsigned short* __restrict__ wf,
                                                   float* __restrict__ part, int n4) {
  const int t = threadIdx.x;
  if (blockIdx.x < 160) {
    // block b = octet (c, kt, lh); thread = o. Reads coef[o][dense v..v+8)
    // contiguous; writes lane-coalesced within segment.
    int b = blockIdx.x;
    int c = b / 10, r = b - c * 10;
    int kt = r >> 1, lh = r & 1;
    int o = t;
    const float* cp = coef + (size_t)o * 1280 + c * 80 + lh * 40 + kt * 8;
    const float* sp = scale + o * 256 + c * 16 + lh * 8;
    ushort8 v;
    #pragma unroll
    for (int j = 0; j < 8; ++j) {
      int il = (kt * 8 + j) / 5;             // input offset within half
      v[j] = f2bf(cp[j] * sp[il]);
    }
    int seg = (c * 8 + (o >> 5)) * 5 + kt;
    *(ushort8*)(wf + (size_t)seg * 512 + (lh * 32 + (o & 31)) * 8) = v;
  } else {
    int mb = blockIdx.x - 160;             // [0, NMB)
    const float4* x4 = (const float4*)x;
    int i = mb * 256 + t;
    float lmin = 1e30f, lmax = -1e30f;
    #pragma unroll
    for (int k = 0; k < 4; ++k) {
      float4 v = x4[i + k * (NMB * 256)];
      lmin = fminf(lmin, fminf(fminf(v.x, v.y), fminf(v.z, v.w)));
      lmax = fmaxf(lmax, fmaxf(fmaxf(v.x, v.y), fmaxf(v.z, v.w)));
    }
    #pragma unroll
    for (int off = 32; off >= 1; off >>= 1) {
      lmin = fminf(lmin, __shfl_down(lmin, off, 64));
      lmax = fmaxf(lmax, __shfl_down(lmax, off, 64));
    }
    __shared__ float smn[4], smx[4];
    if ((t & 63) == 0) { smn[t >> 6] = lmin; smx[t >> 6] = lmax; }
    __syncthreads();
    if (t == 0) {
      part[2 * mb]     = fminf(fminf(smn[0], smn[1]), fminf(smn[2], smn[3]));
      part[2 * mb + 1] = fmaxf(fmaxf(smx[0], smx[1]), fmaxf(smx[2], smx[3]));
    }
  }
}

// Quintet: 5 normalized basis values packed as 3 u32 of bf16 (trunc):
//   u0 = (g0, g1), u1 = (g2, g3), u2 = (g4, -) -- ~32 VALU.
struct quint { unsigned u0, u1, u2; };

__device__ __forceinline__ quint quintet(float xval, float scA, float scB) {
  float xn = fmaf(xval, scA, scB);
  float d0 = xn + 1.0f, d1 = xn + 0.5f, d3 = xn - 0.5f, d4 = xn - 1.0f;
  float b0 = fmaxf(fmaf(d0 * d0, -fabsf(d0), 1.0f), 0.0f);
  float b1 = fmaxf(fmaf(d1 * d1, -fabsf(d1), 1.0f), 0.0f);
  float b2 = fmaxf(fmaf(xn * xn, -fabsf(xn), 1.0f), 0.0f);
  float b3 = fmaxf(fmaf(d3 * d3, -fabsf(d3), 1.0f), 0.0f);
  float b4 = fmaxf(fmaf(d4 * d4, -fabsf(d4), 1.0f), 0.0f);
  float sum = ((b0 + b1) + (b2 + b3)) + b4;
  float inv = __builtin_amdgcn_rcpf(sum);
  b0 *= inv; b1 *= inv; b2 *= inv; b3 *= inv; b4 *= inv;
  quint q;
  q.u0 = __builtin_amdgcn_perm(__float_as_uint(b1), __float_as_uint(b0), PKHH);
  q.u1 = __builtin_amdgcn_perm(__float_as_uint(b3), __float_as_uint(b2), PKHH);
  q.u2 = __float_as_uint(b4) >> 16;
  return q;
}

__global__ void __launch_bounds__(256, 2) kan_gemm(
    const float* __restrict__ x,            // [32768][256]
    const unsigned short* __restrict__ wf,  // 5-dense fragment W, 640 KB
    const float* __restrict__ bias,         // [256]
    const float* __restrict__ part,         // NMB {min,max} partials
    float* __restrict__ out)                // [32768][256]
{
  // B chunk buffers: [buf][ seg = kt*4 + oTl ][ lane*16B ] -> 2 x 20 KB
  __shared__ __align__(16) unsigned short Bb[2][10240];
  __shared__ float2 red[4];

  const int t = threadIdx.x;
  const int lane = t & 63;
  const int wm = t >> 6;                     // 4 waves stacked in m
  const int l31 = lane & 31, lh = lane >> 5;
  const int bRow = blockIdx.x * 128;
  const int bCol = blockIdx.y * 128;
  const int row = bRow + wm * 32 + l31;      // this lane's A row

  // ---- B staging: 20 segments of 1 KB; wave wm DMAs oTl=wm, kt=0..4 ----
  auto stage = [&](int c, int buf) {
    #pragma unroll
    for (int r = 0; r < 5; ++r) {
      const unsigned short* src = wf +
          ((size_t)((c * 8 + blockIdx.y * 4 + wm) * 5 + r)) * 512 + (size_t)lane * 8;
      __builtin_amdgcn_global_load_lds(
          (const __attribute__((address_space(1))) unsigned int*)src,
          (__attribute__((address_space(3))) unsigned int*)(&Bb[buf][(r * 4 + wm) * 512 + lane * 8]),
          16, 0, 0);
    }
  };

  const float* xrow = x + (size_t)row * IN_SZ;

  // prologue: chunk 0 DMA + chunk-0 x loads in flight during minmax reduce
  stage(0, 0);
  float4 xq[4], xqn[4];
  #pragma unroll
  for (int g = 0; g < 4; ++g) xq[g] = *(const float4*)(xrow + g * 4);

  float mn = 1e30f, mx = -1e30f;
  const float2* part2 = (const float2*)part;
  #pragma unroll
  for (int k = 0; k < NMB / 256; ++k) {
    float2 p = part2[k * 256 + t];
    mn = fminf(mn, p.x); mx = fmaxf(mx, p.y);
  }
  #pragma unroll
  for (int off = 32; off >= 1; off >>= 1) {
    mn = fminf(mn, __shfl_down(mn, off, 64));
    mx = fmaxf(mx, __shfl_down(mx, off, 64));
  }
  if (lane == 0) red[wm] = make_float2(mn, mx);
  __syncthreads();
  mn = fminf(fminf(red[0].x, red[1].x), fminf(red[2].x, red[3].x));
  mx = fmaxf(fmaxf(red[0].y, red[1].y), fmaxf(red[2].y, red[3].y));
  const float scA = 2.0f / (mx - mn + EPSF);
  const float scB = -mn * scA - 1.0f;

  floatx16 acc[4] = {};
  bf16x8 br[2][4];                           // [kt parity][oTl]

  auto ldsB = [&](int kt, int buf, bf16x8* dst) {
    #pragma unroll
    for (int q = 0; q < 4; ++q)
      dst[q] = *(const bf16x8*)(&Bb[buf][(kt * 4 + q) * 512 + lane * 8]);
  };

  // ---- K loop: 16 chunks x BK=80 (5 kt of K16); ONE barrier per chunk ----
  for (int c = 0; c < 16; ++c) {
    const int buf = c & 1;

    __syncthreads();   // drain == chunk-c DMA ready (issued 1 chunk ago);
                       // also fences prev-buf LDS reads.

    if (c < 15) {      // next chunk's DMA + x loads in flight for a full chunk
      stage(c + 1, buf ^ 1);
      #pragma unroll
      for (int g = 0; g < 4; ++g)
        xqn[g] = *(const float4*)(xrow + (c + 1) * 16 + g * 4);
    }

    ldsB(0, buf, br[0]);                     // chunk-leading fragment load

    // 8 quintets on lh-selected inputs [c*16 + lh*8, +8) -- no divergence.
    float4 xa = lh ? xq[2] : xq[0];
    float4 xb = lh ? xq[3] : xq[1];
    quint q0 = quintet(xa.x, scA, scB), q1 = quintet(xa.y, scA, scB);
    quint q2 = quintet(xa.z, scA, scB), q3 = quintet(xa.w, scA, scB);
    quint q4 = quintet(xb.x, scA, scB), q5 = quintet(xb.y, scA, scB);
    quint q6 = quintet(xb.z, scA, scB), q7 = quintet(xb.w, scA, scB);

    frag_u a;
    bf16x8* B;

    // kt=0: slots (q0 g0-4, q1 g0-2)
    ldsB(1, buf, br[1]);
    a.u.x = q0.u0; a.u.y = q0.u1;
    a.u.z = __builtin_amdgcn_perm(q1.u0, q0.u2, PKLL);
    a.u.w = __builtin_amdgcn_perm(q1.u1, q1.u0, PKHL);
    B = br[0];
    #pragma unroll
    for (int ni = 0; ni < 4; ++ni)
      acc[ni] = __builtin_amdgcn_mfma_f32_32x32x16_bf16(a.v, B[ni], acc[ni], 0, 0, 0);

    // kt=1: (q1 g3-4, q2 g0-4, q3 g0)
    ldsB(2, buf, br[0]);
    a.u.x = __builtin_amdgcn_perm(q1.u2, q1.u1, PKHL);
    a.u.y = q2.u0; a.u.z = q2.u1;
    a.u.w = __builtin_amdgcn_perm(q3.u0, q2.u2, PKLL);
    B = br[1];
    #pragma unroll
    for (int ni = 0; ni < 4; ++ni)
      acc[ni] = __builtin_amdgcn_mfma_f32_32x32x16_bf16(a.v, B[ni], acc[ni], 0, 0, 0);

    // kt=2: (q3 g1-4, q4 g0-3)
    ldsB(3, buf, br[1]);
    a.u.x = __builtin_amdgcn_perm(q3.u1, q3.u0, PKHL);
    a.u.y = __builtin_amdgcn_perm(q3.u2, q3.u1, PKHL);
    a.u.z = q4.u0; a.u.w = q4.u1;
    B = br[0];
    #pragma unroll
    for (int ni = 0; ni < 4; ++ni)
      acc[ni] = __builtin_amdgcn_mfma_f32_32x32x16_bf16(a.v, B[ni], acc[ni], 0, 0, 0);

    // kt=3: (q4 g4, q5 g0-4, q6 g0-1)
    ldsB(4, buf, br[0]);
    a.u.x = __builtin_amdgcn_perm(q5.u0, q4.u2, PKLL);
    a.u.y = __builtin_amdgcn_perm(q5.u1, q5.u0, PKHL);
    a.u.z = __builtin_amdgcn_perm(q5.u2, q5.u1, PKHL);
    a.u.w = q6.u0;
    B = br[1];
    #pragma unroll
    for (int ni = 0; ni < 4; ++ni)
      acc[ni] = __builtin_amdgcn_mfma_f32_32x32x16_bf16(a.v, B[ni], acc[ni], 0, 0, 0);

    // kt=4: (q6 g2-4, q7 g0-4)
    a.u.x = q6.u1;
    a.u.y = __builtin_amdgcn_perm(q7.u0, q6.u2, PKLL);
    a.u.z = __builtin_amdgcn_perm(q7.u1, q7.u0, PKHL);
    a.u.w = __builtin_amdgcn_perm(q7.u2, q7.u1, PKHL);
    B = br[0];
    #pragma unroll
    for (int ni = 0; ni < 4; ++ni)
      acc[ni] = __builtin_amdgcn_mfma_f32_32x32x16_bf16(a.v, B[ni], acc[ni], 0, 0, 0);

    if (c < 15) {
      #pragma unroll
      for (int g = 0; g < 4; ++g) xq[g] = xqn[g];
    }
  }

  // epilogue: C/D col=lane&31, row=(reg&3)+8*(reg>>2)+4*(lane>>5) [m74/m101]
  #pragma unroll
  for (int ni = 0; ni < 4; ++ni) {
    int o = bCol + ni * 32 + l31;
    float bs = bias[o];
    int rb = bRow + wm * 32 + 4 * lh;
    #pragma unroll
    for (int reg = 0; reg < 16; ++reg) {
      int r = rb + (reg & 3) + 8 * (reg >> 2);
      out[(size_t)r * OUT_SZ + o] = acc[ni][reg] + bs;
    }
  }
}

extern "C" void kernel_launch(void* const* d_in, const int* in_sizes, int n_in,
                              void* d_out, int out_size, void* d_ws, size_t ws_size,
                              hipStream_t stream) {
  const float* x     = (const float*)d_in[0];
  // d_in[1] = grid: linspace(-1,1,5), hardcoded
  const float* coef  = (const float*)d_in[2];
  const float* scale = (const float*)d_in[3];
  const float* bias  = (const float*)d_in[4];
  float* out = (float*)d_out;

  // ws: [0..NMB*8) minmax partials (NMB float2), [16384..) Wf (640 KB)
  size_t need = 16384 + (size_t)640 * 1024;
  if (ws_size < need) return;

  float* part = (float*)d_ws;
  unsigned short* wf = (unsigned short*)((char*)d_ws + 16384);

  prep_kernel<<<160 + NMB, 256, 0, stream>>>(coef, scale, x, wf, part,
                                             (B_SZ * IN_SZ) / 4);
  dim3 g(B_SZ / 128, OUT_SZ / 128);
  kan_gemm<<<g, 256, 0, stream>>>(x, wf, bias, part, out);
}

// Round 11
// 119.931 us; speedup vs baseline: 1.2121x; 1.0287x over previous
//
#include <hip/hip_runtime.h>
#include <stdint.h>

// KAN layer as bf16 MFMA GEMM, 5-dense K=1280, BARRIER-FREE K-loop.
// R18 == R17 with the macro compile fix (#pragma unroll cannot appear in a
//   macro body -> B-loads hand-unrolled). Design unchanged:
//   - W streams L2->registers: per K16, 4 global_load_dwordx4 (1KB segs,
//     lane-linear), distance-2 prefetch into 4 static slots (slot = kt&3;
//     20-kt unrolled body, 20 % 4 == 0 -> stable slot pattern).
//   - ZERO s_barrier in the K loop: waves free-run, 2 waves/SIMD dovetail
//     (quintet burst of one under MFMAs of the other -- m114 overlap).
//   Rationale: R16 accounting shows ~58% stall with no pipe busy; the
//   K-independent residual (~31us) is the per-chunk barrier convoy
//   (m233: stage+vmcnt+barrier = 72% of 2-phase wall). R8 proved counted
//   waits under a barrier are neutral; this removes the barrier itself.
//   W = 640KB -> L2-resident (320KB per by-half per XCD); L2 traffic
//   ~2.6MB/CU ~ 16TB/s < 34.5 ceiling; latency ~200cy < 2-kt distance.

#define B_SZ   32768
#define IN_SZ  256
#define OUT_SZ 256
#define EPSF   1e-8f
#define NMB    2048   // minmax partial blocks

typedef __bf16 bf16x8 __attribute__((ext_vector_type(8)));
typedef unsigned short ushort8 __attribute__((ext_vector_type(8)));
typedef float floatx16 __attribute__((ext_vector_type(16)));

union frag_u { uint4 u; bf16x8 v; };

#define PKHH 0x07060302u
#define PKLL 0x05040100u
#define PKHL 0x05040302u

__device__ __forceinline__ unsigned short f2bf(float f) {
  unsigned u = __float_as_uint(f);
  u += 0x7FFFu + ((u >> 16) & 1u);
  return (unsigned short)(u >> 16);
}

// Dense-pack layout (R16-verified): value v in input-block c = lh*40+kt*8+j,
//   (i_local,g) = (v/5, v%5), i = c*16+i_local. Segment (c,oTg,kt) = 1 KB
//   lane-linear: seg = (c*8 + oTg)*5 + kt, lane l holds bytes [l*16,l*16+16).

// Fused prep: blocks [0,160) pack W 5-dense; [160,160+NMB) min/max partials.
__global__ void __launch_bounds__(256) prep_kernel(const float* __restrict__ coef,
                                                   const float* __restrict__ scale,
                                                   const float* __restrict__ x,
                                                   unsigned short* __restrict__ wf,
                                                   float* __restrict__ part, int n4) {
  const int t = threadIdx.x;
  if (blockIdx.x < 160) {
    int b = blockIdx.x;
    int c = b / 10, r = b - c * 10;
    int kt = r >> 1, lh = r & 1;
    int o = t;
    const float* cp = coef + (size_t)o * 1280 + c * 80 + lh * 40 + kt * 8;
    const float* sp = scale + o * 256 + c * 16 + lh * 8;
    ushort8 v;
    #pragma unroll
    for (int j = 0; j < 8; ++j) {
      int il = (kt * 8 + j) / 5;             // input offset within half
      v[j] = f2bf(cp[j] * sp[il]);
    }
    int seg = (c * 8 + (o >> 5)) * 5 + kt;
    *(ushort8*)(wf + (size_t)seg * 512 + (lh * 32 + (o & 31)) * 8) = v;
  } else {
    int mb = blockIdx.x - 160;             // [0, NMB)
    const float4* x4 = (const float4*)x;
    int i = mb * 256 + t;
    float lmin = 1e30f, lmax = -1e30f;
    #pragma unroll
    for (int k = 0; k < 4; ++k) {
      float4 v = x4[i + k * (NMB * 256)];
      lmin = fminf(lmin, fminf(fminf(v.x, v.y), fminf(v.z, v.w)));
      lmax = fmaxf(lmax, fmaxf(fmaxf(v.x, v.y), fmaxf(v.z, v.w)));
    }
    #pragma unroll
    for (int off = 32; off >= 1; off >>= 1) {
      lmin = fminf(lmin, __shfl_down(lmin, off, 64));
      lmax = fmaxf(lmax, __shfl_down(lmax, off, 64));
    }
    __shared__ float smn[4], smx[4];
    if ((t & 63) == 0) { smn[t >> 6] = lmin; smx[t >> 6] = lmax; }
    __syncthreads();
    if (t == 0) {
      part[2 * mb]     = fminf(fminf(smn[0], smn[1]), fminf(smn[2], smn[3]));
      part[2 * mb + 1] = fmaxf(fmaxf(smx[0], smx[1]), fmaxf(smx[2], smx[3]));
    }
  }
}

// Quintet: 5 normalized basis values packed as 3 u32 of bf16 (trunc).
struct quint { unsigned u0, u1, u2; };

__device__ __forceinline__ quint quintet(float xval, float scA, float scB) {
  float xn = fmaf(xval, scA, scB);
  float d0 = xn + 1.0f, d1 = xn + 0.5f, d3 = xn - 0.5f, d4 = xn - 1.0f;
  float b0 = fmaxf(fmaf(d0 * d0, -fabsf(d0), 1.0f), 0.0f);
  float b1 = fmaxf(fmaf(d1 * d1, -fabsf(d1), 1.0f), 0.0f);
  float b2 = fmaxf(fmaf(xn * xn, -fabsf(xn), 1.0f), 0.0f);
  float b3 = fmaxf(fmaf(d3 * d3, -fabsf(d3), 1.0f), 0.0f);
  float b4 = fmaxf(fmaf(d4 * d4, -fabsf(d4), 1.0f), 0.0f);
  float sum = ((b0 + b1) + (b2 + b3)) + b4;
  float inv = __builtin_amdgcn_rcpf(sum);
  b0 *= inv; b1 *= inv; b2 *= inv; b3 *= inv; b4 *= inv;
  quint q;
  q.u0 = __builtin_amdgcn_perm(__float_as_uint(b1), __float_as_uint(b0), PKHH);
  q.u1 = __builtin_amdgcn_perm(__float_as_uint(b3), __float_as_uint(b2), PKHH);
  q.u2 = __float_as_uint(b4) >> 16;
  return q;
}

// 5-phase A-fragment assembly (R16-verified tables).
template<int R>
__device__ __forceinline__ bf16x8 assembleA(const quint* q) {
  frag_u a;
  if constexpr (R == 0) {
    a.u.x = q[0].u0;
    a.u.y = q[0].u1;
    a.u.z = __builtin_amdgcn_perm(q[1].u0, q[0].u2, PKLL);
    a.u.w = __builtin_amdgcn_perm(q[1].u1, q[1].u0, PKHL);
  } else if constexpr (R == 1) {
    a.u.x = __builtin_amdgcn_perm(q[1].u2, q[1].u1, PKHL);
    a.u.y = q[2].u0;
    a.u.z = q[2].u1;
    a.u.w = __builtin_amdgcn_perm(q[3].u0, q[2].u2, PKLL);
  } else if constexpr (R == 2) {
    a.u.x = __builtin_amdgcn_perm(q[3].u1, q[3].u0, PKHL);
    a.u.y = __builtin_amdgcn_perm(q[3].u2, q[3].u1, PKHL);
    a.u.z = q[4].u0;
    a.u.w = q[4].u1;
  } else if constexpr (R == 3) {
    a.u.x = __builtin_amdgcn_perm(q[5].u0, q[4].u2, PKLL);
    a.u.y = __builtin_amdgcn_perm(q[5].u1, q[5].u0, PKHL);
    a.u.z = __builtin_amdgcn_perm(q[5].u2, q[5].u1, PKHL);
    a.u.w = q[6].u0;
  } else {
    a.u.x = q[6].u1;
    a.u.y = __builtin_amdgcn_perm(q[7].u0, q[6].u2, PKLL);
    a.u.z = __builtin_amdgcn_perm(q[7].u1, q[7].u0, PKHL);
    a.u.w = __builtin_amdgcn_perm(q[7].u2, q[7].u1, PKHL);
  }
  return a.v;
}

// J = kt index within the 20-kt unrolled body (compile-time).
// consume slot J&3 (issued 2 kt ago), prefetch kt+2 into slot (J+2)&3.
// (B-loads hand-unrolled: no #pragma inside macro bodies.)
#define PHASE(J, R)                                                          \
  {                                                                          \
    constexpr int cc2 = ((J) + 2) / 5, rr2 = ((J) + 2) % 5;                  \
    const int c2 = o4 + cc2;                                                 \
    Bs[((J) + 2) & 3][0] = wfl[((c2 * 8 + 0) * 5 + rr2) * 64];               \
    Bs[((J) + 2) & 3][1] = wfl[((c2 * 8 + 1) * 5 + rr2) * 64];               \
    Bs[((J) + 2) & 3][2] = wfl[((c2 * 8 + 2) * 5 + rr2) * 64];               \
    Bs[((J) + 2) & 3][3] = wfl[((c2 * 8 + 3) * 5 + rr2) * 64];               \
    bf16x8 a = assembleA<R>(qq);                                             \
    frag_u b0, b1, b2, b3;                                                   \
    b0.u = Bs[(J) & 3][0]; b1.u = Bs[(J) & 3][1];                            \
    b2.u = Bs[(J) & 3][2]; b3.u = Bs[(J) & 3][3];                            \
    __builtin_amdgcn_s_setprio(1);                                           \
    acc[0] = __builtin_amdgcn_mfma_f32_32x32x16_bf16(a, b0.v, acc[0], 0,0,0);\
    acc[1] = __builtin_amdgcn_mfma_f32_32x32x16_bf16(a, b1.v, acc[1], 0,0,0);\
    acc[2] = __builtin_amdgcn_mfma_f32_32x32x16_bf16(a, b2.v, acc[2], 0,0,0);\
    acc[3] = __builtin_amdgcn_mfma_f32_32x32x16_bf16(a, b3.v, acc[3], 0,0,0);\
    __builtin_amdgcn_s_setprio(0);                                           \
  }

// Group GG (of 4 per outer iter): issue next group's x loads, quintet
// burst from current x, then 5 phases. PREF guarded at the last group.
#define GROUP(GG, XC0, XC1, XN0, XN1, PREF)                                  \
  {                                                                          \
    if (PREF) {                                                              \
      XN0 = *(const float4*)(xrowh + (o4 + (GG) + 1) * 16);                  \
      XN1 = *(const float4*)(xrowh + (o4 + (GG) + 1) * 16 + 4);              \
    }                                                                        \
    quint qq[8];                                                             \
    qq[0] = quintet(XC0.x, scA, scB); qq[1] = quintet(XC0.y, scA, scB);      \
    qq[2] = quintet(XC0.z, scA, scB); qq[3] = quintet(XC0.w, scA, scB);      \
    qq[4] = quintet(XC1.x, scA, scB); qq[5] = quintet(XC1.y, scA, scB);      \
    qq[6] = quintet(XC1.z, scA, scB); qq[7] = quintet(XC1.w, scA, scB);      \
    PHASE((GG) * 5 + 0, 0)                                                   \
    PHASE((GG) * 5 + 1, 1)                                                   \
    PHASE((GG) * 5 + 2, 2)                                                   \
    PHASE((GG) * 5 + 3, 3)                                                   \
    PHASE((GG) * 5 + 4, 4)                                                   \
  }

__global__ void __launch_bounds__(256, 2) kan_gemm(
    const float* __restrict__ x,            // [32768][256]
    const unsigned short* __restrict__ wf,  // 5-dense fragment W, 640 KB
    const float* __restrict__ bias,         // [256]
    const float* __restrict__ part,         // NMB {min,max} partials
    float* __restrict__ out)                // [32768][256]
{
  __shared__ float2 red[4];                 // minmax reduce only (no LDS tile)

  const int t = threadIdx.x;
  const int lane = t & 63;
  const int wm = t >> 6;                     // 4 waves stacked in m
  const int l31 = lane & 31, lh = lane >> 5;
  const int bRow = blockIdx.x * 128;
  const int bCol = blockIdx.y * 128;
  const int row = bRow + wm * 32 + l31;      // this lane's A row

  // lane-based W pointer (uint4 units); by-half folded into base:
  //   seg = (c*8 + by*4 + ni)*5 + kt = by*20 + (c*8+ni)*5 + kt.
  const uint4* wfl = (const uint4*)wf + (size_t)blockIdx.y * 1280 + lane;

  // this lane's x: its row, its lh-half of each 16-input group.
  const float* xrowh = x + (size_t)row * IN_SZ + lh * 8;

  // prologue: B slots 0,1 (kt 0,1) + group-0 x in flight during the reduce
  // (the reduce's __syncthreads drains them once -- one-time cost).
  uint4 Bs[4][4];                            // [slot][ni]
  Bs[0][0] = wfl[((0 * 8 + 0) * 5 + 0) * 64];
  Bs[0][1] = wfl[((0 * 8 + 1) * 5 + 0) * 64];
  Bs[0][2] = wfl[((0 * 8 + 2) * 5 + 0) * 64];
  Bs[0][3] = wfl[((0 * 8 + 3) * 5 + 0) * 64];
  Bs[1][0] = wfl[((0 * 8 + 0) * 5 + 1) * 64];
  Bs[1][1] = wfl[((0 * 8 + 1) * 5 + 1) * 64];
  Bs[1][2] = wfl[((0 * 8 + 2) * 5 + 1) * 64];
  Bs[1][3] = wfl[((0 * 8 + 3) * 5 + 1) * 64];
  float4 xA0 = *(const float4*)(xrowh);
  float4 xA1 = *(const float4*)(xrowh + 4);
  float4 xB0, xB1;

  float mn = 1e30f, mx = -1e30f;
  const float2* part2 = (const float2*)part;
  #pragma unroll
  for (int k = 0; k < NMB / 256; ++k) {
    float2 p = part2[k * 256 + t];
    mn = fminf(mn, p.x); mx = fmaxf(mx, p.y);
  }
  #pragma unroll
  for (int off = 32; off >= 1; off >>= 1) {
    mn = fminf(mn, __shfl_down(mn, off, 64));
    mx = fmaxf(mx, __shfl_down(mx, off, 64));
  }
  if (lane == 0) red[wm] = make_float2(mn, mx);
  __syncthreads();
  mn = fminf(fminf(red[0].x, red[1].x), fminf(red[2].x, red[3].x));
  mx = fmaxf(fmaxf(red[0].y, red[1].y), fmaxf(red[2].y, red[3].y));
  const float scA = 2.0f / (mx - mn + EPSF);
  const float scB = -mn * scA - 1.0f;

  floatx16 acc[4] = {};

  // ---- K loop: 4 outer x 20 kt (4 groups of 5); NO barriers, no LDS ----
  // slot = kt & 3 is outer-invariant (20 % 4 == 0). Last outer's j=18,19
  // prefetch c=16 (overread into ws slack, never consumed).
  for (int o = 0, o4 = 0; o < 4; ++o, o4 += 4) {
    GROUP(0, xA0, xA1, xB0, xB1, true)
    GROUP(1, xB0, xB1, xA0, xA1, true)
    GROUP(2, xA0, xA1, xB0, xB1, true)
    GROUP(3, xB0, xB1, xA0, xA1, (o4 < 12))
  }

  // epilogue: C/D col=lane&31, row=(reg&3)+8*(reg>>2)+4*(lane>>5) [m74/m101]
  #pragma unroll
  for (int ni = 0; ni < 4; ++ni) {
    int o = bCol + ni * 32 + l31;
    float bs = bias[o];
    int rb = bRow + wm * 32 + 4 * lh;
    #pragma unroll
    for (int reg = 0; reg < 16; ++reg) {
      int r = rb + (reg & 3) + 8 * (reg >> 2);
      out[(size_t)r * OUT_SZ + o] = acc[ni][reg] + bs;
    }
  }
}

extern "C" void kernel_launch(void* const* d_in, const int* in_sizes, int n_in,
                              void* d_out, int out_size, void* d_ws, size_t ws_size,
                              hipStream_t stream) {
  const float* x     = (const float*)d_in[0];
  // d_in[1] = grid: linspace(-1,1,5), hardcoded
  const float* coef  = (const float*)d_in[2];
  const float* scale = (const float*)d_in[3];
  const float* bias  = (const float*)d_in[4];
  float* out = (float*)d_out;

  // ws: [0..NMB*8) minmax partials, [16384..) Wf (640 KB + 64 KB
  // prefetch-overread slack for the tail phases).
  size_t need = 16384 + (size_t)704 * 1024;
  if (ws_size < need) return;

  float* part = (float*)d_ws;
  unsigned short* wf = (unsigned short*)((char*)d_ws + 16384);

  prep_kernel<<<160 + NMB, 256, 0, stream>>>(coef, scale, x, wf, part,
                                             (B_SZ * IN_SZ) / 4);
  dim3 g(B_SZ / 128, OUT_SZ / 128);
  kan_gemm<<<g, 256, 0, stream>>>(x, wf, bias, part, out);
}